// Round 5
// baseline (473.154 us; speedup 1.0000x reference)
//
#include <hip/hip_runtime.h>
#include <math.h>

typedef _Float16 f16;
typedef _Float16 f16x8 __attribute__((ext_vector_type(8)));
typedef _Float16 f16x4 __attribute__((ext_vector_type(4)));
typedef __fp16 fp16x2 __attribute__((ext_vector_type(2)));
typedef float f32x4 __attribute__((ext_vector_type(4)));

#define NM 16384   // nodes (K of big GEMM)
#define NE 4096    // hyperedges
#define ND 300     // feature dim
#define DP 320     // padded feature dim
#define JT 640     // 2*DP columns of Z

__device__ __forceinline__ int swz(int r) { return (r ^ (r >> 2)) & 3; }

#define GLOAD_LDS16(gsrc, ldst)                                              \
  __builtin_amdgcn_global_load_lds(                                          \
      (__attribute__((address_space(1))) void*)(gsrc),                       \
      (__attribute__((address_space(3))) void*)(ldst), 16, 0, 0)

// ---------------------------------------------------------------- k0: W_att^T -> fp16 (DPxDP)
__global__ void k0_wt(const float* __restrict__ Watt, f16* __restrict__ WT) {
  int idx = blockIdx.x * 256 + threadIdx.x;
  if (idx >= DP * DP) return;
  int j = idx / DP, d = idx % DP;
  float v = (j < ND && d < ND) ? Watt[d * ND + j] : 0.f;
  WT[(size_t)j * DP + d] = (f16)v;
}

// ---------------------------------------------------------------- k1a: X -> X16 [m][DP] and YT rows 320..639 (X^T)
__global__ __launch_bounds__(256) void k1a_xprep(const float* __restrict__ X,
                                                 f16* __restrict__ X16,
                                                 f16* __restrict__ YT) {
  __shared__ f16 tile[64][324];
  int m0 = blockIdx.x * 64;
  for (int idx = threadIdx.x; idx < 64 * 80; idx += 256) {
    int m = idx / 80, q = idx % 80;
    int d = q * 4;
    float4 v = make_float4(0.f, 0.f, 0.f, 0.f);
    if (d < ND) v = *(const float4*)(X + (size_t)(m0 + m) * ND + d);
    f16x4 hv;
    hv[0] = (f16)v.x; hv[1] = (f16)v.y; hv[2] = (f16)v.z; hv[3] = (f16)v.w;
    tile[m][d] = hv[0]; tile[m][d + 1] = hv[1];
    tile[m][d + 2] = hv[2]; tile[m][d + 3] = hv[3];
    *(f16x4*)(X16 + (size_t)(m0 + m) * DP + d) = hv;
  }
  __syncthreads();
  for (int idx = threadIdx.x; idx < DP * 8; idx += 256) {
    int d = idx >> 3, part = idx & 7;
    f16x8 hv;
#pragma unroll
    for (int i = 0; i < 8; ++i) hv[i] = tile[part * 8 + i][d];
    *(f16x8*)(YT + (size_t)(DP + d) * NM + m0 + part * 8) = hv;
  }
}

// ---------------------------------------------------------------- k1b: YT rows 0..319 = W^T @ X^T (fp16 MFMA)
__global__ __launch_bounds__(512, 2) void k1b_xat(const f16* __restrict__ WT,
                                                  const f16* __restrict__ X16,
                                                  f16* __restrict__ YT) {
  __shared__ __align__(16) char lds[49152];
  const int t = threadIdx.x, lane = t & 63, wid = t >> 6;
  const int m0 = blockIdx.x * 64;
  const int row = lane & 15, g = lane >> 4;
  const int wj = wid & 3, wm = wid >> 2;
  int aoff[5], boff[2];
#pragma unroll
  for (int f = 0; f < 5; ++f) {
    int jr = wj * 80 + f * 16 + row;
    aoff[f] = jr * 64 + ((g ^ swz(jr)) << 4);
  }
#pragma unroll
  for (int fm = 0; fm < 2; ++fm) {
    int mr = wm * 32 + fm * 16 + row;
    boff[fm] = mr * 64 + ((g ^ swz(mr)) << 4);
  }
  f32x4 acc[5][2];
#pragma unroll
  for (int f = 0; f < 5; ++f)
#pragma unroll
    for (int fm = 0; fm < 2; ++fm)
#pragma unroll
      for (int r = 0; r < 4; ++r) acc[f][fm][r] = 0.f;

  auto stage = [&](int buf, int ks) {
    int k0 = ks * 32;
    char* A = lds + buf * 20480;
    char* B = lds + 40960 + buf * 4096;
    for (int c = wid; c < 24; c += 8) {
      if (c < 20) {
        int j = c * 16 + (lane >> 2), gg = lane & 3;
        GLOAD_LDS16(WT + (size_t)j * DP + k0 + 8 * (gg ^ swz(j)), A + c * 1024);
      } else {
        int cb = c - 20;
        int m = cb * 16 + (lane >> 2), gg = lane & 3;
        GLOAD_LDS16(X16 + (size_t)(m0 + m) * DP + k0 + 8 * (gg ^ swz(m)),
                    B + cb * 1024);
      }
    }
  };
  stage(0, 0);
  __syncthreads();
  for (int ks = 0; ks < 10; ++ks) {
    int cur = ks & 1;
    if (ks + 1 < 10) stage(cur ^ 1, ks + 1);
    const char* A = lds + cur * 20480;
    const char* B = lds + 40960 + cur * 4096;
    f16x8 b0 = *(const f16x8*)(B + boff[0]);
    f16x8 b1 = *(const f16x8*)(B + boff[1]);
#pragma unroll
    for (int f = 0; f < 5; ++f) {
      f16x8 a = *(const f16x8*)(A + aoff[f]);
      acc[f][0] = __builtin_amdgcn_mfma_f32_16x16x32_f16(a, b0, acc[f][0], 0, 0, 0);
      acc[f][1] = __builtin_amdgcn_mfma_f32_16x16x32_f16(a, b1, acc[f][1], 0, 0, 0);
    }
    __syncthreads();
  }
#pragma unroll
  for (int f = 0; f < 5; ++f)
#pragma unroll
    for (int fm = 0; fm < 2; ++fm)
#pragma unroll
      for (int r = 0; r < 4; ++r) {
        int j = wj * 80 + f * 16 + g * 4 + r;
        int m = m0 + wm * 32 + fm * 16 + row;
        YT[(size_t)j * NM + m] = (f16)acc[f][fm][r];
      }
}

// ---------------------------------------------------------------- k2 v4: Z = inc^T @ Y, split-K x2
// grid 512 = 64 eb x 4 jn x 2 kb; block 256 thr (4 waves, wave 32e x 80j);
// BK=64, ring-2 LDS double buffer, 2 raw barriers/step, counted vmcnt.
// LDS: Bbuf[2] @ 0 / 20480 (160 rows x 128B); Abuf[2] @ 40960 / 49152 (64 rows x 128B)
#define K2WAIT(N) asm volatile("s_waitcnt vmcnt(" #N ") lgkmcnt(0)" ::: "memory")
#define K2BAR()                                        \
  do {                                                 \
    asm volatile("" ::: "memory");                     \
    __builtin_amdgcn_s_barrier();                      \
    asm volatile("" ::: "memory");                     \
  } while (0)

__global__ __launch_bounds__(256, 2) void k2_bigmm(const float* __restrict__ inc,
                                                   const f16* __restrict__ YT,
                                                   float* __restrict__ Z0,
                                                   float* __restrict__ Z1) {
  __shared__ __align__(16) char lds[57344];
  const int t = threadIdx.x, lane = t & 63, wid = t >> 6;
  const int bx = blockIdx.x;
  const int eb = bx >> 3, jn = (bx >> 1) & 3, kb = bx & 1;
  const int e0 = eb * 64, j0 = jn * 160;
  const size_t kbase = (size_t)kb * 8192;
  float* __restrict__ Zout = kb ? Z1 : Z0;

  const int we = wid >> 1, wj = wid & 1;
  const int r15 = lane & 15, g = lane >> 4, l7 = lane & 7;

  int aaddr[2], baddr[2];
#pragma unroll
  for (int kk = 0; kk < 2; ++kk) {
    aaddr[kk] = (we * 32 + r15) * 128 + ((((kk * 4 + g) ^ l7) & 7) << 4) + 40960;
    baddr[kk] = (wj * 80 + r15) * 128 + ((((kk * 4 + g) ^ l7) & 7) << 4);
  }
  const int ep = t & 31, kq = t >> 5;
  int wadr[2];
#pragma unroll
  for (int j = 0; j < 2; ++j) {
    int e = 2 * ep + j;
    wadr[j] = e * 128 + (((kq ^ (e & 7)) & 7) << 4) + 40960;
  }
  const float* pA[8];
#pragma unroll
  for (int i = 0; i < 8; ++i)
    pA[i] = inc + (kbase + kq * 8 + i) * NE + e0 + 2 * ep;
  const f16* pB[5];
#pragma unroll
  for (int i = 0; i < 5; ++i) {
    int row = wid * 40 + i * 8 + (lane >> 3);
    pB[i] = YT + (size_t)(j0 + row) * NM + kbase + 8 * ((l7 ^ (lane >> 3)) & 7);
  }

  float rA0[16], rA1[16];
  f32x4 acc[2][5];
#pragma unroll
  for (int ef = 0; ef < 2; ++ef)
#pragma unroll
    for (int f = 0; f < 5; ++f)
#pragma unroll
      for (int r = 0; r < 4; ++r) acc[ef][f][r] = 0.f;

#define LOADA(R)                                                               \
  {                                                                            \
    _Pragma("unroll") for (int i = 0; i < 8; ++i) {                            \
      float2 v_ = *(const float2*)pA[i];                                       \
      R[2 * i] = v_.x; R[2 * i + 1] = v_.y;                                    \
      pA[i] += (size_t)64 * NE;                                                \
    }                                                                          \
  }
#define DMAB(S)                                                                \
  {                                                                            \
    _Pragma("unroll") for (int i = 0; i < 5; ++i) {                            \
      GLOAD_LDS16(pB[i], lds + (S)*20480 + (wid * 5 + i) * 1024);              \
      pB[i] += 64;                                                             \
    }                                                                          \
  }
#define WRITEA(R, S)                                                           \
  {                                                                            \
    union { fp16x2 h; uint32_t u; } cx_[4], cy_[4];                            \
    _Pragma("unroll") for (int z = 0; z < 4; ++z) {                            \
      cx_[z].h = __builtin_amdgcn_cvt_pkrtz(R[4 * z], R[4 * z + 2]);           \
      cy_[z].h = __builtin_amdgcn_cvt_pkrtz(R[4 * z + 1], R[4 * z + 3]);       \
    }                                                                          \
    *(uint4*)(lds + wadr[0] + (S)*8192) =                                      \
        make_uint4(cx_[0].u, cx_[1].u, cx_[2].u, cx_[3].u);                    \
    *(uint4*)(lds + wadr[1] + (S)*8192) =                                      \
        make_uint4(cy_[0].u, cy_[1].u, cy_[2].u, cy_[3].u);                    \
  }
#define COMPUTE(S)                                                             \
  {                                                                            \
    __builtin_amdgcn_s_setprio(1);                                             \
    _Pragma("unroll") for (int kk = 0; kk < 2; ++kk) {                         \
      f16x8 a0_ = *(const f16x8*)(lds + aaddr[kk] + (S)*8192);                 \
      f16x8 a1_ = *(const f16x8*)(lds + aaddr[kk] + (S)*8192 + 2048);          \
      _Pragma("unroll") for (int f = 0; f < 5; ++f) {                          \
        f16x8 b_ = *(const f16x8*)(lds + baddr[kk] + (S)*20480 + f * 2048);    \
        acc[0][f] = __builtin_amdgcn_mfma_f32_16x16x32_f16(a0_, b_, acc[0][f], 0, 0, 0); \
        acc[1][f] = __builtin_amdgcn_mfma_f32_16x16x32_f16(a1_, b_, acc[1][f], 0, 0, 0); \
      }                                                                        \
    }                                                                          \
    __builtin_amdgcn_s_setprio(0);                                             \
  }

  // prologue: A(0)->rA0, A(1)->rA1, B(0)->Bbuf0, write A(0), A(2)->rA0
  LOADA(rA0);
  LOADA(rA1);
  DMAB(0);
  WRITEA(rA0, 0);
  LOADA(rA0);

  // main loop: steps 0..123 (62 x 2)
  for (int it = 0; it < 62; ++it) {
    // even step t: write A(t+1), load A(t+3)->rA1, dma B(t+1)
    WRITEA(rA1, 1); LOADA(rA1); DMAB(1);
    K2WAIT(13); K2BAR();
    COMPUTE(0); K2BAR();
    // odd step t+1: write A(t+2), load A(t+4)->rA0, dma B(t+2)
    WRITEA(rA0, 0); LOADA(rA0); DMAB(0);
    K2WAIT(13); K2BAR();
    COMPUTE(1); K2BAR();
  }
  // t=124: last A-load (A(127))
  WRITEA(rA1, 1); LOADA(rA1); DMAB(1);
  K2WAIT(13); K2BAR();
  COMPUTE(0); K2BAR();
  // t=125: no A-load; dma B(126)
  WRITEA(rA0, 0); DMAB(0);
  K2WAIT(5); K2BAR();
  COMPUTE(1); K2BAR();
  // t=126: no A-load; dma B(127)
  WRITEA(rA1, 1); DMAB(1);
  K2WAIT(5); K2BAR();
  COMPUTE(0); K2BAR();
  // t=127: drain
  K2WAIT(0); K2BAR();
  COMPUTE(1);

  // epilogue: store partial C
#pragma unroll
  for (int ef = 0; ef < 2; ++ef)
#pragma unroll
    for (int f = 0; f < 5; ++f) {
      int jgl = j0 + wj * 80 + f * 16 + r15;
#pragma unroll
      for (int r = 0; r < 4; ++r) {
        int egl = e0 + we * 32 + ef * 16 + g * 4 + r;
        Zout[(size_t)egl * JT + jgl] = acc[ef][f][r];
      }
    }
#undef LOADA
#undef DMAB
#undef WRITEA
#undef COMPUTE
}

// ---------------------------------------------------------------- k3: per-edge softmax + projection + residual + scores
__global__ __launch_bounds__(256) void k3_edge(const float* __restrict__ Z0,
                                               const float* __restrict__ Z1,
                                               const float* __restrict__ edge_feats,
                                               const float* __restrict__ Wproj,
                                               const float* __restrict__ alphaP,
                                               const float* __restrict__ ecWatt,
                                               float* __restrict__ ef,
                                               float* __restrict__ scores) {
  __shared__ float efw[16][304];
  const int t = threadIdx.x, lane = t & 63, w = t >> 6;
  const int e0 = blockIdx.x * 16;
  for (int el = 0; el < 4; ++el) {
    int e = e0 + w * 4 + el;
    const float* zr0 = Z0 + (size_t)e * JT;
    const float* zr1 = Z1 + (size_t)e * JT;
    float p[5];
    float mx = -1e30f;
#pragma unroll
    for (int u = 0; u < 5; ++u) {
      int d = u * 64 + lane;
      p[u] = (d < ND) ? (zr0[d] + zr1[d]) : -1e30f;
      mx = fmaxf(mx, p[u]);
    }
    for (int o = 32; o; o >>= 1) mx = fmaxf(mx, __shfl_xor(mx, o));
    float s = 0.f;
#pragma unroll
    for (int u = 0; u < 5; ++u) {
      int d = u * 64 + lane;
      float pe = (d < ND) ? expf(p[u] - mx) : 0.f;
      p[u] = pe;
      s += pe;
    }
    for (int o = 32; o; o >>= 1) s += __shfl_xor(s, o);
    float inv = 1.f / s;
#pragma unroll
    for (int u = 0; u < 5; ++u) {
      int d = u * 64 + lane;
      if (d < 304)
        efw[w * 4 + el][d] = (d < ND) ? (zr0[DP + d] + zr1[DP + d]) * p[u] * inv : 0.f;
    }
  }
  __syncthreads();
  const int el = t >> 4, jl = t & 15;
  const int e = e0 + el;
  const float alpha = alphaP[0];
  const float* efwr = efw[el];
  float acc[19];
#pragma unroll
  for (int jj = 0; jj < 19; ++jj) acc[jj] = 0.f;
  for (int d = 0; d < ND; ++d) {
    float ew = efwr[d];
    const float* wr = Wproj + d * ND + jl;
#pragma unroll
    for (int jj = 0; jj < 19; ++jj) {
      int j = jl + jj * 16;
      if (j < ND) acc[jj] += ew * wr[jj * 16];
    }
  }
  float sc = 0.f;
#pragma unroll
  for (int jj = 0; jj < 19; ++jj) {
    int j = jl + jj * 16;
    float v = 0.f;
    if (j < ND) {
      v = alpha * edge_feats[(size_t)e * ND + j] + (1.f - alpha) * acc[jj];
      sc += v * ecWatt[j];
    }
    ef[(size_t)e * 304 + j] = v;
  }
  for (int o = 8; o; o >>= 1) sc += __shfl_xor(sc, o, 16);
  if (jl == 0) scores[e] = sc;
}

// ---------------------------------------------------------------- k4a: softmax over 4096 edge scores
__global__ __launch_bounds__(1024) void k4a_softmax(const float* __restrict__ scores,
                                                    float* __restrict__ w) {
  __shared__ float red[16];
  __shared__ float red2[16];
  const int t = threadIdx.x, lane = t & 63, wv = t >> 6;
  float v[4];
  float mx = -1e30f;
#pragma unroll
  for (int u = 0; u < 4; ++u) {
    v[u] = scores[t + u * 1024];
    mx = fmaxf(mx, v[u]);
  }
  for (int o = 32; o; o >>= 1) mx = fmaxf(mx, __shfl_xor(mx, o));
  if (lane == 0) red[wv] = mx;
  __syncthreads();
  float m2 = red[0];
  for (int i = 1; i < 16; ++i) m2 = fmaxf(m2, red[i]);
  float s = 0.f;
#pragma unroll
  for (int u = 0; u < 4; ++u) {
    v[u] = expf(v[u] - m2);
    s += v[u];
  }
  for (int o = 32; o; o >>= 1) s += __shfl_xor(s, o);
  if (lane == 0) red2[wv] = s;
  __syncthreads();
  float S = 0.f;
  for (int i = 0; i < 16; ++i) S += red2[i];
  float inv = 1.f / S;
#pragma unroll
  for (int u = 0; u < 4; ++u) w[t + u * 1024] = v[u] * inv;
}

// ---------------------------------------------------------------- k4b: partial weighted pooling (64 edges/block)
__global__ __launch_bounds__(256) void k4b_pool(const float* __restrict__ ef,
                                                const float* __restrict__ w,
                                                float* __restrict__ partial) {
  const int b = blockIdx.x, t = threadIdx.x;
  const int e0 = b * 64;
  for (int j = t; j < 304; j += 256) {
    float acc = 0.f;
    for (int e = 0; e < 64; ++e) acc += w[e0 + e] * ef[(size_t)(e0 + e) * 304 + j];
    partial[b * 304 + j] = acc;
  }
}

// ---------------------------------------------------------------- k4c: final reduce + two matvecs -> 3 logits
__global__ __launch_bounds__(256) void k4c_final(const float* __restrict__ partial,
                                                 const float* __restrict__ ecWp,
                                                 const float* __restrict__ ecb,
                                                 const float* __restrict__ fcW,
                                                 const float* __restrict__ fcb,
                                                 float* __restrict__ out) {
  __shared__ float pooled[304];
  __shared__ float o[304];
  const int t = threadIdx.x;
  for (int j = t; j < 304; j += 256) {
    float acc = 0.f;
    for (int b = 0; b < 64; ++b) acc += partial[b * 304 + j];
    pooled[j] = acc;
  }
  __syncthreads();
  for (int j2 = t; j2 < ND; j2 += 256) {
    float acc = ecb[j2];
    for (int j = 0; j < ND; ++j) acc += pooled[j] * ecWp[j * ND + j2];
    o[j2] = acc;
  }
  __syncthreads();
  if (t < 3) {
    float acc = fcb[t];
    for (int j2 = 0; j2 < ND; ++j2) acc += o[j2] * fcW[j2 * 3 + t];
    out[t] = acc;
  }
}

// ----------------------------------------------------------------
extern "C" void kernel_launch(void* const* d_in, const int* in_sizes, int n_in,
                              void* d_out, int out_size, void* d_ws, size_t ws_size,
                              hipStream_t stream) {
  const float* X = (const float*)d_in[0];
  const float* EF = (const float*)d_in[1];
  const float* INC = (const float*)d_in[2];
  const float* WATT = (const float*)d_in[3];
  const float* WPROJ = (const float*)d_in[4];
  const float* ALPHA = (const float*)d_in[5];
  const float* ECATT = (const float*)d_in[6];
  const float* ECWP = (const float*)d_in[7];
  const float* ECB = (const float*)d_in[8];
  const float* FCW = (const float*)d_in[9];
  const float* FCB = (const float*)d_in[10];

  char* ws = (char*)d_ws;
  f16* YT = (f16*)(ws);                      // 640*16384*2  = 20971520
  f16* X16 = (f16*)(ws + 20971520);          // 16384*320*2  = 10485760 (dead after k1b)
  float* Z1 = (float*)(ws + 20971520);       // 4096*640*4   = 10485760 (aliases X16)
  f16* WT = (f16*)(ws + 31457280);           // 320*320*2    =   204800
  float* Z0 = (float*)(ws + 31662080);       // 4096*640*4   = 10485760
  float* ef = (float*)(ws + 42147840);       // 4096*304*4   =  4980736
  float* sc = (float*)(ws + 47128576);       // 4096*4
  float* wv = (float*)(ws + 47144960);       // 4096*4
  float* pp = (float*)(ws + 47161344);       // 64*304*4

  hipLaunchKernelGGL(k0_wt, dim3(400), dim3(256), 0, stream, WATT, WT);
  hipLaunchKernelGGL(k1a_xprep, dim3(256), dim3(256), 0, stream, X, X16, YT);
  hipLaunchKernelGGL(k1b_xat, dim3(256), dim3(512), 0, stream, WT, X16, YT);
  hipLaunchKernelGGL(k2_bigmm, dim3(512), dim3(256), 0, stream, INC, YT, Z0, Z1);
  hipLaunchKernelGGL(k3_edge, dim3(256), dim3(256), 0, stream, Z0, Z1, EF, WPROJ,
                     ALPHA, ECATT, ef, sc);
  hipLaunchKernelGGL(k4a_softmax, dim3(1), dim3(1024), 0, stream, sc, wv);
  hipLaunchKernelGGL(k4b_pool, dim3(64), dim3(256), 0, stream, ef, wv, pp);
  hipLaunchKernelGGL(k4c_final, dim3(1), dim3(256), 0, stream, pp, ECWP, ECB, FCW,
                     FCB, (float*)d_out);
}

// Round 6
// 322.552 us; speedup vs baseline: 1.4669x; 1.4669x over previous
//
#include <hip/hip_runtime.h>
#include <math.h>

typedef _Float16 f16;
typedef _Float16 f16x8 __attribute__((ext_vector_type(8)));
typedef _Float16 f16x4 __attribute__((ext_vector_type(4)));
typedef __fp16 fp16x2 __attribute__((ext_vector_type(2)));
typedef float f32x4 __attribute__((ext_vector_type(4)));

#define NM 16384   // nodes (K of big GEMM)
#define NE 4096    // hyperedges
#define ND 300     // feature dim
#define DP 320     // padded feature dim
#define JT 640     // 2*DP columns of Z

__device__ __forceinline__ int swz(int r) { return (r ^ (r >> 2)) & 3; }

#define GLOAD_LDS16(gsrc, ldst)                                              \
  __builtin_amdgcn_global_load_lds(                                          \
      (__attribute__((address_space(1))) void*)(gsrc),                       \
      (__attribute__((address_space(3))) void*)(ldst), 16, 0, 0)

// ---------------------------------------------------------------- k0: W_att^T -> fp16 (DPxDP)
__global__ void k0_wt(const float* __restrict__ Watt, f16* __restrict__ WT) {
  int idx = blockIdx.x * 256 + threadIdx.x;
  if (idx >= DP * DP) return;
  int j = idx / DP, d = idx % DP;
  float v = (j < ND && d < ND) ? Watt[d * ND + j] : 0.f;
  WT[(size_t)j * DP + d] = (f16)v;
}

// ---------------------------------------------------------------- k1a: X -> X16 [m][DP] and YT rows 320..639 (X^T)
__global__ __launch_bounds__(256) void k1a_xprep(const float* __restrict__ X,
                                                 f16* __restrict__ X16,
                                                 f16* __restrict__ YT) {
  __shared__ f16 tile[64][324];
  int m0 = blockIdx.x * 64;
  for (int idx = threadIdx.x; idx < 64 * 80; idx += 256) {
    int m = idx / 80, q = idx % 80;
    int d = q * 4;
    float4 v = make_float4(0.f, 0.f, 0.f, 0.f);
    if (d < ND) v = *(const float4*)(X + (size_t)(m0 + m) * ND + d);
    f16x4 hv;
    hv[0] = (f16)v.x; hv[1] = (f16)v.y; hv[2] = (f16)v.z; hv[3] = (f16)v.w;
    tile[m][d] = hv[0]; tile[m][d + 1] = hv[1];
    tile[m][d + 2] = hv[2]; tile[m][d + 3] = hv[3];
    *(f16x4*)(X16 + (size_t)(m0 + m) * DP + d) = hv;
  }
  __syncthreads();
  for (int idx = threadIdx.x; idx < DP * 8; idx += 256) {
    int d = idx >> 3, part = idx & 7;
    f16x8 hv;
#pragma unroll
    for (int i = 0; i < 8; ++i) hv[i] = tile[part * 8 + i][d];
    *(f16x8*)(YT + (size_t)(DP + d) * NM + m0 + part * 8) = hv;
  }
}

// ---------------------------------------------------------------- k1b: YT rows 0..319 = W^T @ X^T (fp16 MFMA)
__global__ __launch_bounds__(512, 2) void k1b_xat(const f16* __restrict__ WT,
                                                  const f16* __restrict__ X16,
                                                  f16* __restrict__ YT) {
  __shared__ __align__(16) char lds[49152];
  const int t = threadIdx.x, lane = t & 63, wid = t >> 6;
  const int m0 = blockIdx.x * 64;
  const int row = lane & 15, g = lane >> 4;
  const int wj = wid & 3, wm = wid >> 2;
  int aoff[5], boff[2];
#pragma unroll
  for (int f = 0; f < 5; ++f) {
    int jr = wj * 80 + f * 16 + row;
    aoff[f] = jr * 64 + ((g ^ swz(jr)) << 4);
  }
#pragma unroll
  for (int fm = 0; fm < 2; ++fm) {
    int mr = wm * 32 + fm * 16 + row;
    boff[fm] = mr * 64 + ((g ^ swz(mr)) << 4);
  }
  f32x4 acc[5][2];
#pragma unroll
  for (int f = 0; f < 5; ++f)
#pragma unroll
    for (int fm = 0; fm < 2; ++fm)
#pragma unroll
      for (int r = 0; r < 4; ++r) acc[f][fm][r] = 0.f;

  auto stage = [&](int buf, int ks) {
    int k0 = ks * 32;
    char* A = lds + buf * 20480;
    char* B = lds + 40960 + buf * 4096;
    for (int c = wid; c < 24; c += 8) {
      if (c < 20) {
        int j = c * 16 + (lane >> 2), gg = lane & 3;
        GLOAD_LDS16(WT + (size_t)j * DP + k0 + 8 * (gg ^ swz(j)), A + c * 1024);
      } else {
        int cb = c - 20;
        int m = cb * 16 + (lane >> 2), gg = lane & 3;
        GLOAD_LDS16(X16 + (size_t)(m0 + m) * DP + k0 + 8 * (gg ^ swz(m)),
                    B + cb * 1024);
      }
    }
  };
  stage(0, 0);
  __syncthreads();
  for (int ks = 0; ks < 10; ++ks) {
    int cur = ks & 1;
    if (ks + 1 < 10) stage(cur ^ 1, ks + 1);
    const char* A = lds + cur * 20480;
    const char* B = lds + 40960 + cur * 4096;
    f16x8 b0 = *(const f16x8*)(B + boff[0]);
    f16x8 b1 = *(const f16x8*)(B + boff[1]);
#pragma unroll
    for (int f = 0; f < 5; ++f) {
      f16x8 a = *(const f16x8*)(A + aoff[f]);
      acc[f][0] = __builtin_amdgcn_mfma_f32_16x16x32_f16(a, b0, acc[f][0], 0, 0, 0);
      acc[f][1] = __builtin_amdgcn_mfma_f32_16x16x32_f16(a, b1, acc[f][1], 0, 0, 0);
    }
    __syncthreads();
  }
#pragma unroll
  for (int f = 0; f < 5; ++f)
#pragma unroll
    for (int fm = 0; fm < 2; ++fm)
#pragma unroll
      for (int r = 0; r < 4; ++r) {
        int j = wj * 80 + f * 16 + g * 4 + r;
        int m = m0 + wm * 32 + fm * 16 + row;
        YT[(size_t)j * NM + m] = (f16)acc[f][fm][r];
      }
}

// ---------------------------------------------------------------- k2 v5: Z = inc^T @ Y, split-K x2
// grid 512; decode so XCD = bx&7 = (eb%4)*2+kb -> all 4 jn-siblings of an
// (eb,kb) share one XCD's L2 (inc fetched once per byte). 256 thr, 4 waves,
// BK=64, ring-2 LDS double buffer, 2 raw barriers/step, counted vmcnt.
// LDS: Bbuf[2] @ 0 / 20480 (160 rows x 128B); Abuf[2] @ 40960 / 49152 (64 rows x 128B)
#define K2WAIT(N) asm volatile("s_waitcnt vmcnt(" #N ") lgkmcnt(0)" ::: "memory")
#define K2BAR()                                        \
  do {                                                 \
    asm volatile("" ::: "memory");                     \
    __builtin_amdgcn_s_barrier();                      \
    asm volatile("" ::: "memory");                     \
  } while (0)

__global__ __launch_bounds__(256, 2) void k2_bigmm(const float* __restrict__ inc,
                                                   const f16* __restrict__ YT,
                                                   float* __restrict__ Z0,
                                                   float* __restrict__ Z1) {
  __shared__ __align__(16) char lds[57344];
  const int t = threadIdx.x, lane = t & 63, wid = t >> 6;
  const int bx = blockIdx.x;
  const int xcd = bx & 7, y = bx >> 3;
  const int kb = xcd & 1, ebl = xcd >> 1;
  const int jn = y & 3, eb = (y >> 2) * 4 + ebl;
  const int e0 = eb * 64, j0 = jn * 160;
  const size_t kbase = (size_t)kb * 8192;
  float* __restrict__ Zout = kb ? Z1 : Z0;

  const int we = wid >> 1, wj = wid & 1;
  const int r15 = lane & 15, g = lane >> 4, l7 = lane & 7;

  int aaddr[2], baddr[2];
#pragma unroll
  for (int kk = 0; kk < 2; ++kk) {
    aaddr[kk] = (we * 32 + r15) * 128 + ((((kk * 4 + g) ^ l7) & 7) << 4) + 40960;
    baddr[kk] = (wj * 80 + r15) * 128 + ((((kk * 4 + g) ^ l7) & 7) << 4);
  }
  const int ep = t & 31, kq = t >> 5;
  int wadr[2];
#pragma unroll
  for (int j = 0; j < 2; ++j) {
    int e = 2 * ep + j;
    wadr[j] = e * 128 + (((kq ^ (e & 7)) & 7) << 4) + 40960;
  }
  const float* pA[8];
#pragma unroll
  for (int i = 0; i < 8; ++i)
    pA[i] = inc + (kbase + kq * 8 + i) * NE + e0 + 2 * ep;
  const f16* pB[5];
#pragma unroll
  for (int i = 0; i < 5; ++i) {
    int row = wid * 40 + i * 8 + (lane >> 3);
    pB[i] = YT + (size_t)(j0 + row) * NM + kbase + 8 * ((l7 ^ (lane >> 3)) & 7);
  }

  float rA0[16], rA1[16];
  f32x4 acc[2][5];
#pragma unroll
  for (int ef = 0; ef < 2; ++ef)
#pragma unroll
    for (int f = 0; f < 5; ++f)
#pragma unroll
      for (int r = 0; r < 4; ++r) acc[ef][f][r] = 0.f;

#define LOADA(R)                                                               \
  {                                                                            \
    _Pragma("unroll") for (int i = 0; i < 8; ++i) {                            \
      float2 v_ = *(const float2*)pA[i];                                       \
      R[2 * i] = v_.x; R[2 * i + 1] = v_.y;                                    \
      pA[i] += (size_t)64 * NE;                                                \
    }                                                                          \
  }
#define DMAB(S)                                                                \
  {                                                                            \
    _Pragma("unroll") for (int i = 0; i < 5; ++i) {                            \
      GLOAD_LDS16(pB[i], lds + (S)*20480 + (wid * 5 + i) * 1024);              \
      pB[i] += 64;                                                             \
    }                                                                          \
  }
#define WRITEA(R, S)                                                           \
  {                                                                            \
    union { fp16x2 h; uint32_t u; } cx_[4], cy_[4];                            \
    _Pragma("unroll") for (int z = 0; z < 4; ++z) {                            \
      cx_[z].h = __builtin_amdgcn_cvt_pkrtz(R[4 * z], R[4 * z + 2]);           \
      cy_[z].h = __builtin_amdgcn_cvt_pkrtz(R[4 * z + 1], R[4 * z + 3]);       \
    }                                                                          \
    *(uint4*)(lds + wadr[0] + (S)*8192) =                                      \
        make_uint4(cx_[0].u, cx_[1].u, cx_[2].u, cx_[3].u);                    \
    *(uint4*)(lds + wadr[1] + (S)*8192) =                                      \
        make_uint4(cy_[0].u, cy_[1].u, cy_[2].u, cy_[3].u);                    \
  }
#define COMPUTE(S)                                                             \
  {                                                                            \
    __builtin_amdgcn_s_setprio(1);                                             \
    _Pragma("unroll") for (int kk = 0; kk < 2; ++kk) {                         \
      f16x8 a0_ = *(const f16x8*)(lds + aaddr[kk] + (S)*8192);                 \
      f16x8 a1_ = *(const f16x8*)(lds + aaddr[kk] + (S)*8192 + 2048);          \
      _Pragma("unroll") for (int f = 0; f < 5; ++f) {                          \
        f16x8 b_ = *(const f16x8*)(lds + baddr[kk] + (S)*20480 + f * 2048);    \
        acc[0][f] = __builtin_amdgcn_mfma_f32_16x16x32_f16(a0_, b_, acc[0][f], 0, 0, 0); \
        acc[1][f] = __builtin_amdgcn_mfma_f32_16x16x32_f16(a1_, b_, acc[1][f], 0, 0, 0); \
      }                                                                        \
    }                                                                          \
    __builtin_amdgcn_s_setprio(0);                                             \
  }

  // prologue: A(0)->rA0, A(1)->rA1, B(0)->Bbuf0, write A(0), A(2)->rA0
  LOADA(rA0);
  LOADA(rA1);
  DMAB(0);
  WRITEA(rA0, 0);
  LOADA(rA0);

  // main loop: steps 0..123 (62 x 2)
  for (int it = 0; it < 62; ++it) {
    // even step t: write A(t+1), load A(t+3)->rA1, dma B(t+1)
    WRITEA(rA1, 1); LOADA(rA1); DMAB(1);
    K2WAIT(13); K2BAR();
    COMPUTE(0); K2BAR();
    // odd step t+1: write A(t+2), load A(t+4)->rA0, dma B(t+2)
    WRITEA(rA0, 0); LOADA(rA0); DMAB(0);
    K2WAIT(13); K2BAR();
    COMPUTE(1); K2BAR();
  }
  // t=124: last A-load (A(127))
  WRITEA(rA1, 1); LOADA(rA1); DMAB(1);
  K2WAIT(13); K2BAR();
  COMPUTE(0); K2BAR();
  // t=125: no A-load; dma B(126)
  WRITEA(rA0, 0); DMAB(0);
  K2WAIT(5); K2BAR();
  COMPUTE(1); K2BAR();
  // t=126: no A-load; dma B(127)
  WRITEA(rA1, 1); DMAB(1);
  K2WAIT(5); K2BAR();
  COMPUTE(0); K2BAR();
  // t=127: drain
  K2WAIT(0); K2BAR();
  COMPUTE(1);

  // epilogue: store partial C
#pragma unroll
  for (int ef = 0; ef < 2; ++ef)
#pragma unroll
    for (int f = 0; f < 5; ++f) {
      int jgl = j0 + wj * 80 + f * 16 + r15;
#pragma unroll
      for (int r = 0; r < 4; ++r) {
        int egl = e0 + we * 32 + ef * 16 + g * 4 + r;
        Zout[(size_t)egl * JT + jgl] = acc[ef][f][r];
      }
    }
#undef LOADA
#undef DMAB
#undef WRITEA
#undef COMPUTE
}

// ---------------------------------------------------------------- k3 v2: per-edge softmax + register-blocked projection
// 16 edges/block. Phase 2: wave w -> 4 edges; lane = (kc 4) x (jl 16);
// thread does 4e x 19j x 75d; kc-reduce via shfl_xor(16,32); scores fused.
__global__ __launch_bounds__(256) void k3_edge(const float* __restrict__ Z0,
                                               const float* __restrict__ Z1,
                                               const float* __restrict__ edge_feats,
                                               const float* __restrict__ Wproj,
                                               const float* __restrict__ alphaP,
                                               const float* __restrict__ ecWatt,
                                               float* __restrict__ ef,
                                               float* __restrict__ scores) {
  __shared__ float efw[16][304];
  const int t = threadIdx.x, lane = t & 63, w = t >> 6;
  const int e0 = blockIdx.x * 16;
  // phase 1: feature softmax, weight ef0
  for (int el = 0; el < 4; ++el) {
    int e = e0 + w * 4 + el;
    const float* zr0 = Z0 + (size_t)e * JT;
    const float* zr1 = Z1 + (size_t)e * JT;
    float p[5];
    float mx = -1e30f;
#pragma unroll
    for (int u = 0; u < 5; ++u) {
      int d = u * 64 + lane;
      p[u] = (d < ND) ? (zr0[d] + zr1[d]) : -1e30f;
      mx = fmaxf(mx, p[u]);
    }
    for (int o = 32; o; o >>= 1) mx = fmaxf(mx, __shfl_xor(mx, o));
    float s = 0.f;
#pragma unroll
    for (int u = 0; u < 5; ++u) {
      int d = u * 64 + lane;
      float pe = (d < ND) ? expf(p[u] - mx) : 0.f;
      p[u] = pe;
      s += pe;
    }
    for (int o = 32; o; o >>= 1) s += __shfl_xor(s, o);
    float inv = 1.f / s;
#pragma unroll
    for (int u = 0; u < 5; ++u) {
      int d = u * 64 + lane;
      if (d < 304)
        efw[w * 4 + el][d] = (d < ND) ? (zr0[DP + d] + zr1[DP + d]) * p[u] * inv : 0.f;
    }
  }
  __syncthreads();
  // phase 2
  const int jl = lane & 15, kc = lane >> 4;
  const float alpha = alphaP[0];
  float acc[4][19];
#pragma unroll
  for (int ei = 0; ei < 4; ++ei)
#pragma unroll
    for (int jj = 0; jj < 19; ++jj) acc[ei][jj] = 0.f;
  const int d0 = kc * 75;
  const float* efw0 = &efw[w * 4 + 0][0];
  const float* efw1 = &efw[w * 4 + 1][0];
  const float* efw2 = &efw[w * 4 + 2][0];
  const float* efw3 = &efw[w * 4 + 3][0];
  for (int dd = 0; dd < 75; ++dd) {
    int d = d0 + dd;
    const float* wr = Wproj + (size_t)d * ND + jl;
    float w0 = efw0[d], w1 = efw1[d], w2 = efw2[d], w3 = efw3[d];
#pragma unroll
    for (int jj = 0; jj < 19; ++jj) {
      int j = jl + jj * 16;
      float wv = (j < ND) ? wr[jj * 16] : 0.f;
      acc[0][jj] += w0 * wv;
      acc[1][jj] += w1 * wv;
      acc[2][jj] += w2 * wv;
      acc[3][jj] += w3 * wv;
    }
  }
  // reduce over kc (lanes 16-apart)
#pragma unroll
  for (int ei = 0; ei < 4; ++ei)
#pragma unroll
    for (int jj = 0; jj < 19; ++jj) {
      acc[ei][jj] += __shfl_xor(acc[ei][jj], 16);
      acc[ei][jj] += __shfl_xor(acc[ei][jj], 32);
    }
  // epilogue: residual mix, ef store, fused scores
  float scp[4] = {0.f, 0.f, 0.f, 0.f};
#pragma unroll
  for (int ei = 0; ei < 4; ++ei) {
    int e = e0 + w * 4 + ei;
#pragma unroll
    for (int jj = 0; jj < 19; ++jj) {
      int j = jl + jj * 16;
      float v = 0.f;
      if (j < ND) {
        v = alpha * edge_feats[(size_t)e * ND + j] + (1.f - alpha) * acc[ei][jj];
        scp[ei] += v * ecWatt[j];
      }
      if (kc == 0) ef[(size_t)e * 304 + j] = v;
    }
  }
#pragma unroll
  for (int ei = 0; ei < 4; ++ei)
    for (int o = 8; o; o >>= 1) scp[ei] += __shfl_xor(scp[ei], o);
  if (lane == 0) {
#pragma unroll
    for (int ei = 0; ei < 4; ++ei) scores[e0 + w * 4 + ei] = scp[ei];
  }
}

// ---------------------------------------------------------------- k4a: softmax over 4096 edge scores
__global__ __launch_bounds__(1024) void k4a_softmax(const float* __restrict__ scores,
                                                    float* __restrict__ w) {
  __shared__ float red[16];
  __shared__ float red2[16];
  const int t = threadIdx.x, lane = t & 63, wv = t >> 6;
  float v[4];
  float mx = -1e30f;
#pragma unroll
  for (int u = 0; u < 4; ++u) {
    v[u] = scores[t + u * 1024];
    mx = fmaxf(mx, v[u]);
  }
  for (int o = 32; o; o >>= 1) mx = fmaxf(mx, __shfl_xor(mx, o));
  if (lane == 0) red[wv] = mx;
  __syncthreads();
  float m2 = red[0];
  for (int i = 1; i < 16; ++i) m2 = fmaxf(m2, red[i]);
  float s = 0.f;
#pragma unroll
  for (int u = 0; u < 4; ++u) {
    v[u] = expf(v[u] - m2);
    s += v[u];
  }
  for (int o = 32; o; o >>= 1) s += __shfl_xor(s, o);
  if (lane == 0) red2[wv] = s;
  __syncthreads();
  float S = 0.f;
  for (int i = 0; i < 16; ++i) S += red2[i];
  float inv = 1.f / S;
#pragma unroll
  for (int u = 0; u < 4; ++u) w[t + u * 1024] = v[u] * inv;
}

// ---------------------------------------------------------------- k4b: partial weighted pooling (64 edges/block)
__global__ __launch_bounds__(256) void k4b_pool(const float* __restrict__ ef,
                                                const float* __restrict__ w,
                                                float* __restrict__ partial) {
  const int b = blockIdx.x, t = threadIdx.x;
  const int e0 = b * 64;
  for (int j = t; j < 304; j += 256) {
    float acc = 0.f;
    for (int e = 0; e < 64; ++e) acc += w[e0 + e] * ef[(size_t)(e0 + e) * 304 + j];
    partial[b * 304 + j] = acc;
  }
}

// ---------------------------------------------------------------- k4c: final reduce + two matvecs -> 3 logits
__global__ __launch_bounds__(256) void k4c_final(const float* __restrict__ partial,
                                                 const float* __restrict__ ecWp,
                                                 const float* __restrict__ ecb,
                                                 const float* __restrict__ fcW,
                                                 const float* __restrict__ fcb,
                                                 float* __restrict__ out) {
  __shared__ float pooled[304];
  __shared__ float o[304];
  const int t = threadIdx.x;
  for (int j = t; j < 304; j += 256) {
    float acc = 0.f;
    for (int b = 0; b < 64; ++b) acc += partial[b * 304 + j];
    pooled[j] = acc;
  }
  __syncthreads();
  for (int j2 = t; j2 < ND; j2 += 256) {
    float acc = ecb[j2];
    for (int j = 0; j < ND; ++j) acc += pooled[j] * ecWp[j * ND + j2];
    o[j2] = acc;
  }
  __syncthreads();
  if (t < 3) {
    float acc = fcb[t];
    for (int j2 = 0; j2 < ND; ++j2) acc += o[j2] * fcW[j2 * 3 + t];
    out[t] = acc;
  }
}

// ----------------------------------------------------------------
extern "C" void kernel_launch(void* const* d_in, const int* in_sizes, int n_in,
                              void* d_out, int out_size, void* d_ws, size_t ws_size,
                              hipStream_t stream) {
  const float* X = (const float*)d_in[0];
  const float* EF = (const float*)d_in[1];
  const float* INC = (const float*)d_in[2];
  const float* WATT = (const float*)d_in[3];
  const float* WPROJ = (const float*)d_in[4];
  const float* ALPHA = (const float*)d_in[5];
  const float* ECATT = (const float*)d_in[6];
  const float* ECWP = (const float*)d_in[7];
  const float* ECB = (const float*)d_in[8];
  const float* FCW = (const float*)d_in[9];
  const float* FCB = (const float*)d_in[10];

  char* ws = (char*)d_ws;
  f16* YT = (f16*)(ws);                      // 640*16384*2  = 20971520
  f16* X16 = (f16*)(ws + 20971520);          // 16384*320*2  = 10485760 (dead after k1b)
  float* Z1 = (float*)(ws + 20971520);       // 4096*640*4   = 10485760 (aliases X16)
  f16* WT = (f16*)(ws + 31457280);           // 320*320*2    =   204800
  float* Z0 = (float*)(ws + 31662080);       // 4096*640*4   = 10485760
  float* ef = (float*)(ws + 42147840);       // 4096*304*4   =  4980736
  float* sc = (float*)(ws + 47128576);       // 4096*4
  float* wv = (float*)(ws + 47144960);       // 4096*4
  float* pp = (float*)(ws + 47161344);       // 64*304*4

  hipLaunchKernelGGL(k0_wt, dim3(400), dim3(256), 0, stream, WATT, WT);
  hipLaunchKernelGGL(k1a_xprep, dim3(256), dim3(256), 0, stream, X, X16, YT);
  hipLaunchKernelGGL(k1b_xat, dim3(256), dim3(512), 0, stream, WT, X16, YT);
  hipLaunchKernelGGL(k2_bigmm, dim3(512), dim3(256), 0, stream, INC, YT, Z0, Z1);
  hipLaunchKernelGGL(k3_edge, dim3(256), dim3(256), 0, stream, Z0, Z1, EF, WPROJ,
                     ALPHA, ECATT, ef, sc);
  hipLaunchKernelGGL(k4a_softmax, dim3(1), dim3(1024), 0, stream, sc, wv);
  hipLaunchKernelGGL(k4b_pool, dim3(64), dim3(256), 0, stream, ef, wv, pp);
  hipLaunchKernelGGL(k4c_final, dim3(1), dim3(256), 0, stream, pp, ECWP, ECB, FCW,
                     FCB, (float*)d_out);
}

// Round 7
// 321.401 us; speedup vs baseline: 1.4722x; 1.0036x over previous
//
#include <hip/hip_runtime.h>
#include <math.h>

typedef _Float16 f16;
typedef _Float16 f16x8 __attribute__((ext_vector_type(8)));
typedef _Float16 f16x4 __attribute__((ext_vector_type(4)));
typedef __fp16 fp16x2 __attribute__((ext_vector_type(2)));
typedef float f32x4 __attribute__((ext_vector_type(4)));
typedef float f32x16 __attribute__((ext_vector_type(16)));

#define NM 16384   // nodes (K of big GEMM)
#define NE 4096    // hyperedges
#define ND 300     // feature dim
#define DP 320     // padded feature dim
#define JT 640     // 2*DP columns of Z

__device__ __forceinline__ int swz(int r) { return (r ^ (r >> 2)) & 3; }

#define GLOAD_LDS16(gsrc, ldst)                                              \
  __builtin_amdgcn_global_load_lds(                                          \
      (__attribute__((address_space(1))) void*)(gsrc),                       \
      (__attribute__((address_space(3))) void*)(ldst), 16, 0, 0)

// ---------------------------------------------------------------- k0: W_att^T -> fp16 (DPxDP)
__global__ void k0_wt(const float* __restrict__ Watt, f16* __restrict__ WT) {
  int idx = blockIdx.x * 256 + threadIdx.x;
  if (idx >= DP * DP) return;
  int j = idx / DP, d = idx % DP;
  float v = (j < ND && d < ND) ? Watt[d * ND + j] : 0.f;
  WT[(size_t)j * DP + d] = (f16)v;
}

// ---------------------------------------------------------------- k1a: X -> X16 [m][DP] and YT rows 320..639 (X^T)
__global__ __launch_bounds__(256) void k1a_xprep(const float* __restrict__ X,
                                                 f16* __restrict__ X16,
                                                 f16* __restrict__ YT) {
  __shared__ f16 tile[64][324];
  int m0 = blockIdx.x * 64;
  for (int idx = threadIdx.x; idx < 64 * 80; idx += 256) {
    int m = idx / 80, q = idx % 80;
    int d = q * 4;
    float4 v = make_float4(0.f, 0.f, 0.f, 0.f);
    if (d < ND) v = *(const float4*)(X + (size_t)(m0 + m) * ND + d);
    f16x4 hv;
    hv[0] = (f16)v.x; hv[1] = (f16)v.y; hv[2] = (f16)v.z; hv[3] = (f16)v.w;
    tile[m][d] = hv[0]; tile[m][d + 1] = hv[1];
    tile[m][d + 2] = hv[2]; tile[m][d + 3] = hv[3];
    *(f16x4*)(X16 + (size_t)(m0 + m) * DP + d) = hv;
  }
  __syncthreads();
  for (int idx = threadIdx.x; idx < DP * 8; idx += 256) {
    int d = idx >> 3, part = idx & 7;
    f16x8 hv;
#pragma unroll
    for (int i = 0; i < 8; ++i) hv[i] = tile[part * 8 + i][d];
    *(f16x8*)(YT + (size_t)(DP + d) * NM + m0 + part * 8) = hv;
  }
}

// ---------------------------------------------------------------- k1b: YT rows 0..319 = W^T @ X^T (fp16 MFMA)
__global__ __launch_bounds__(512, 2) void k1b_xat(const f16* __restrict__ WT,
                                                  const f16* __restrict__ X16,
                                                  f16* __restrict__ YT) {
  __shared__ __align__(16) char lds[49152];
  const int t = threadIdx.x, lane = t & 63, wid = t >> 6;
  const int m0 = blockIdx.x * 64;
  const int row = lane & 15, g = lane >> 4;
  const int wj = wid & 3, wm = wid >> 2;
  int aoff[5], boff[2];
#pragma unroll
  for (int f = 0; f < 5; ++f) {
    int jr = wj * 80 + f * 16 + row;
    aoff[f] = jr * 64 + ((g ^ swz(jr)) << 4);
  }
#pragma unroll
  for (int fm = 0; fm < 2; ++fm) {
    int mr = wm * 32 + fm * 16 + row;
    boff[fm] = mr * 64 + ((g ^ swz(mr)) << 4);
  }
  f32x4 acc[5][2];
#pragma unroll
  for (int f = 0; f < 5; ++f)
#pragma unroll
    for (int fm = 0; fm < 2; ++fm)
#pragma unroll
      for (int r = 0; r < 4; ++r) acc[f][fm][r] = 0.f;

  auto stage = [&](int buf, int ks) {
    int k0 = ks * 32;
    char* A = lds + buf * 20480;
    char* B = lds + 40960 + buf * 4096;
    for (int c = wid; c < 24; c += 8) {
      if (c < 20) {
        int j = c * 16 + (lane >> 2), gg = lane & 3;
        GLOAD_LDS16(WT + (size_t)j * DP + k0 + 8 * (gg ^ swz(j)), A + c * 1024);
      } else {
        int cb = c - 20;
        int m = cb * 16 + (lane >> 2), gg = lane & 3;
        GLOAD_LDS16(X16 + (size_t)(m0 + m) * DP + k0 + 8 * (gg ^ swz(m)),
                    B + cb * 1024);
      }
    }
  };
  stage(0, 0);
  __syncthreads();
  for (int ks = 0; ks < 10; ++ks) {
    int cur = ks & 1;
    if (ks + 1 < 10) stage(cur ^ 1, ks + 1);
    const char* A = lds + cur * 20480;
    const char* B = lds + 40960 + cur * 4096;
    f16x8 b0 = *(const f16x8*)(B + boff[0]);
    f16x8 b1 = *(const f16x8*)(B + boff[1]);
#pragma unroll
    for (int f = 0; f < 5; ++f) {
      f16x8 a = *(const f16x8*)(A + aoff[f]);
      acc[f][0] = __builtin_amdgcn_mfma_f32_16x16x32_f16(a, b0, acc[f][0], 0, 0, 0);
      acc[f][1] = __builtin_amdgcn_mfma_f32_16x16x32_f16(a, b1, acc[f][1], 0, 0, 0);
    }
    __syncthreads();
  }
#pragma unroll
  for (int f = 0; f < 5; ++f)
#pragma unroll
    for (int fm = 0; fm < 2; ++fm)
#pragma unroll
      for (int r = 0; r < 4; ++r) {
        int j = wj * 80 + f * 16 + g * 4 + r;
        int m = m0 + wm * 32 + fm * 16 + row;
        YT[(size_t)j * NM + m] = (f16)acc[f][fm][r];
      }
}

// ---------------------------------------------------------------- k2 v6: Z = inc^T @ Y with 32x32x16 MFMA
// block 128e x 320j, 4 waves (2e x 2j), wave tile 64e x 160j (Ma=2, Nb=5),
// BK=64, split-K NKB, grid 64*NKB. Ring-2 LDS, counted vmcnt, 2 barriers/step.
// LDS: Bbuf[2] @ 0/40960 (320 rows x 128B); Abuf[2] @ 81920/98304 (128 rows x 128B)
#define K2WAIT(N) asm volatile("s_waitcnt vmcnt(" #N ") lgkmcnt(0)" ::: "memory")
#define K2BAR()                                        \
  do {                                                 \
    asm volatile("" ::: "memory");                     \
    __builtin_amdgcn_s_barrier();                      \
    asm volatile("" ::: "memory");                     \
  } while (0)

template <int NKB>
__global__ __launch_bounds__(256, 1) void k2_bigmm(const float* __restrict__ inc,
                                                   const f16* __restrict__ YT,
                                                   float* __restrict__ Zp0,
                                                   float* __restrict__ Zp1,
                                                   float* __restrict__ Zp2,
                                                   float* __restrict__ Zp3) {
  constexpr int KRANGE = 16384 / NKB;
  constexpr int STEPS = KRANGE / 64;
  __shared__ __align__(16) char lds[114688];
  const int t = threadIdx.x, lane = t & 63, wid = t >> 6;
  const int bx = blockIdx.x;
  const int xcd = bx & 7, local = bx >> 3;
  int eb, jn, kb;
  if (NKB == 4) {
    eb = xcd * 4 + (local >> 3); jn = (local >> 2) & 1; kb = local & 3;
  } else {
    eb = xcd * 4 + (local >> 2); jn = (local >> 1) & 1; kb = local & 1;
  }
  const int e0 = eb * 128, j0 = jn * 320;
  const size_t kbase = (size_t)kb * KRANGE;
  float* __restrict__ Zout = (kb == 0) ? Zp0 : (kb == 1) ? Zp1 : (kb == 2) ? Zp2 : Zp3;

  const int we = wid >> 1, wj = wid & 1;
  const int l31 = lane & 31, oct = lane >> 5, l7 = lane & 7;
  int sl[4];
#pragma unroll
  for (int kk = 0; kk < 4; ++kk) sl[kk] = (((kk * 2 + oct) ^ l7) << 4);
  const int arow = (we * 64 + l31) * 128;
  const int brow = (wj * 160 + l31) * 128;
  // A staging: thread = e-pair(lane) x k-quarter(wid)
  const int kq = wid;
  int wa[4];
  {
    int eA = 2 * lane, eB = 2 * lane + 1;
    wa[0] = eA * 128 + ((((kq * 2 + 0) ^ (eA & 7)) & 7) << 4);
    wa[1] = eA * 128 + ((((kq * 2 + 1) ^ (eA & 7)) & 7) << 4);
    wa[2] = eB * 128 + ((((kq * 2 + 0) ^ (eB & 7)) & 7) << 4);
    wa[3] = eB * 128 + ((((kq * 2 + 1) ^ (eB & 7)) & 7) << 4);
  }
  const float* pA = inc + (kbase + kq * 16) * NE + e0 + 2 * lane;
  const f16* pB = YT + (size_t)(j0 + wid * 80 + (lane >> 3)) * NM + kbase +
                  8 * (l7 ^ ((lane >> 3) & 7));

  float2 rA[16];
  f32x16 acc[2][5];
#pragma unroll
  for (int me = 0; me < 2; ++me)
#pragma unroll
    for (int f = 0; f < 5; ++f)
#pragma unroll
      for (int r = 0; r < 16; ++r) acc[me][f][r] = 0.f;

#define LOADA()                                                                \
  {                                                                            \
    _Pragma("unroll") for (int i = 0; i < 16; ++i)                             \
        rA[i] = *(const float2*)(pA + (size_t)i * NE);                         \
    pA += (size_t)64 * NE;                                                     \
  }
#define DMAB(S)                                                                \
  {                                                                            \
    _Pragma("unroll") for (int c = 0; c < 10; ++c) {                           \
      GLOAD_LDS16(pB + (size_t)(c * 8) * NM,                                   \
                  lds + (S)*40960 + wid * 10240 + c * 1024);                   \
    }                                                                          \
    pB += 64;                                                                  \
  }
#define WRITEA(S)                                                              \
  {                                                                            \
    char* dA_ = lds + 81920 + (S)*16384;                                       \
    union { fp16x2 h; uint32_t u; } c0_[4], c1_[4], c2_[4], c3_[4];            \
    _Pragma("unroll") for (int m = 0; m < 4; ++m) {                            \
      c0_[m].h = __builtin_amdgcn_cvt_pkrtz(rA[2 * m].x, rA[2 * m + 1].x);     \
      c1_[m].h = __builtin_amdgcn_cvt_pkrtz(rA[8 + 2 * m].x, rA[9 + 2 * m].x); \
      c2_[m].h = __builtin_amdgcn_cvt_pkrtz(rA[2 * m].y, rA[2 * m + 1].y);     \
      c3_[m].h = __builtin_amdgcn_cvt_pkrtz(rA[8 + 2 * m].y, rA[9 + 2 * m].y); \
    }                                                                          \
    *(uint4*)(dA_ + wa[0]) = make_uint4(c0_[0].u, c0_[1].u, c0_[2].u, c0_[3].u); \
    *(uint4*)(dA_ + wa[1]) = make_uint4(c1_[0].u, c1_[1].u, c1_[2].u, c1_[3].u); \
    *(uint4*)(dA_ + wa[2]) = make_uint4(c2_[0].u, c2_[1].u, c2_[2].u, c2_[3].u); \
    *(uint4*)(dA_ + wa[3]) = make_uint4(c3_[0].u, c3_[1].u, c3_[2].u, c3_[3].u); \
  }
#define COMPUTE(S)                                                             \
  {                                                                            \
    __builtin_amdgcn_s_setprio(1);                                             \
    _Pragma("unroll") for (int kk = 0; kk < 4; ++kk) {                         \
      f16x8 a0_ = *(const f16x8*)(lds + 81920 + (S)*16384 + arow + sl[kk]);    \
      f16x8 a1_ = *(const f16x8*)(lds + 81920 + (S)*16384 + 4096 + arow + sl[kk]); \
      _Pragma("unroll") for (int f = 0; f < 5; ++f) {                          \
        f16x8 b_ = *(const f16x8*)(lds + (S)*40960 + brow + f * 4096 + sl[kk]); \
        acc[0][f] = __builtin_amdgcn_mfma_f32_32x32x16_f16(a0_, b_, acc[0][f], 0, 0, 0); \
        acc[1][f] = __builtin_amdgcn_mfma_f32_32x32x16_f16(a1_, b_, acc[1][f], 0, 0, 0); \
      }                                                                        \
    }                                                                          \
    __builtin_amdgcn_s_setprio(0);                                             \
  }

  // prologue: A(0),B(0) then A(1),B(1) in flight
  LOADA();        // A(0)
  DMAB(0);        // B(0)
  WRITEA(0);      // waits A(0) via dep
  LOADA();        // A(1)
  DMAB(1);        // B(1)
  K2WAIT(26);     // drain B(0); leave A(1)+B(1)
  K2BAR();

  for (int tt = 0; tt < STEPS - 2; ++tt) {
    COMPUTE(tt & 1);
    K2BAR();                 // all waves done reading buffers of step tt
    WRITEA((tt + 1) & 1);    // rA holds A(tt+1); implicit wait drains its loads
    LOADA();                 // A(tt+2)
    DMAB(tt & 1);            // B(tt+2) into freed buffer
    K2WAIT(26);              // drain B(tt+1)
    K2BAR();
  }
  // tt = STEPS-2
  COMPUTE((STEPS - 2) & 1);
  K2BAR();
  WRITEA((STEPS - 1) & 1);   // rA = A(STEPS-1)
  K2WAIT(0);                 // drain B(STEPS-1)
  K2BAR();
  COMPUTE((STEPS - 1) & 1);

  // epilogue: store partial C (C/D: col=lane&31, row=(r&3)+8*(r>>2)+4*oct)
#pragma unroll
  for (int me = 0; me < 2; ++me)
#pragma unroll
    for (int f = 0; f < 5; ++f) {
      int jg = j0 + wj * 160 + f * 32 + l31;
      int ebase = e0 + we * 64 + me * 32 + 4 * oct;
#pragma unroll
      for (int r = 0; r < 16; ++r) {
        int eg = ebase + (r & 3) + 8 * (r >> 2);
        Zout[(size_t)eg * JT + jg] = acc[me][f][r];
      }
    }
#undef LOADA
#undef DMAB
#undef WRITEA
#undef COMPUTE
}

// ---------------------------------------------------------------- k3 v3: per-edge softmax + register-blocked projection
__global__ __launch_bounds__(256) void k3_edge(const float* __restrict__ Z0,
                                               const float* __restrict__ Z1,
                                               const float* __restrict__ Z2,
                                               const float* __restrict__ Z3,
                                               int nkb,
                                               const float* __restrict__ edge_feats,
                                               const float* __restrict__ Wproj,
                                               const float* __restrict__ alphaP,
                                               const float* __restrict__ ecWatt,
                                               float* __restrict__ ef,
                                               float* __restrict__ scores) {
  __shared__ float efw[16][304];
  const int t = threadIdx.x, lane = t & 63, w = t >> 6;
  const int e0 = blockIdx.x * 16;
  // phase 1: feature softmax, weight ef0
  for (int el = 0; el < 4; ++el) {
    int e = e0 + w * 4 + el;
    const size_t ro = (size_t)e * JT;
    float p[5];
    float mx = -1e30f;
#pragma unroll
    for (int u = 0; u < 5; ++u) {
      int d = u * 64 + lane;
      float zv = -1e30f;
      if (d < ND) {
        zv = Z0[ro + d] + Z1[ro + d];
        if (nkb == 4) zv += Z2[ro + d] + Z3[ro + d];
      }
      p[u] = zv;
      mx = fmaxf(mx, p[u]);
    }
    for (int o = 32; o; o >>= 1) mx = fmaxf(mx, __shfl_xor(mx, o));
    float s = 0.f;
#pragma unroll
    for (int u = 0; u < 5; ++u) {
      int d = u * 64 + lane;
      float pe = (d < ND) ? expf(p[u] - mx) : 0.f;
      p[u] = pe;
      s += pe;
    }
    for (int o = 32; o; o >>= 1) s += __shfl_xor(s, o);
    float inv = 1.f / s;
#pragma unroll
    for (int u = 0; u < 5; ++u) {
      int d = u * 64 + lane;
      if (d < 304) {
        float rv = 0.f;
        if (d < ND) {
          rv = Z0[ro + DP + d] + Z1[ro + DP + d];
          if (nkb == 4) rv += Z2[ro + DP + d] + Z3[ro + DP + d];
          rv *= p[u] * inv;
        }
        efw[w * 4 + el][d] = rv;
      }
    }
  }
  __syncthreads();
  // phase 2: register-blocked (ef0*attn) @ W_proj + residual + scores
  const int jl = lane & 15, kc = lane >> 4;
  const float alpha = alphaP[0];
  float acc[4][19];
#pragma unroll
  for (int ei = 0; ei < 4; ++ei)
#pragma unroll
    for (int jj = 0; jj < 19; ++jj) acc[ei][jj] = 0.f;
  const int d0 = kc * 75;
  const float* efw0 = &efw[w * 4 + 0][0];
  const float* efw1 = &efw[w * 4 + 1][0];
  const float* efw2 = &efw[w * 4 + 2][0];
  const float* efw3 = &efw[w * 4 + 3][0];
  for (int dd = 0; dd < 75; ++dd) {
    int d = d0 + dd;
    const float* wr = Wproj + (size_t)d * ND + jl;
    float w0 = efw0[d], w1 = efw1[d], w2 = efw2[d], w3 = efw3[d];
#pragma unroll
    for (int jj = 0; jj < 19; ++jj) {
      int j = jl + jj * 16;
      float wv = (j < ND) ? wr[jj * 16] : 0.f;
      acc[0][jj] += w0 * wv;
      acc[1][jj] += w1 * wv;
      acc[2][jj] += w2 * wv;
      acc[3][jj] += w3 * wv;
    }
  }
#pragma unroll
  for (int ei = 0; ei < 4; ++ei)
#pragma unroll
    for (int jj = 0; jj < 19; ++jj) {
      acc[ei][jj] += __shfl_xor(acc[ei][jj], 16);
      acc[ei][jj] += __shfl_xor(acc[ei][jj], 32);
    }
  float scp[4] = {0.f, 0.f, 0.f, 0.f};
#pragma unroll
  for (int ei = 0; ei < 4; ++ei) {
    int e = e0 + w * 4 + ei;
#pragma unroll
    for (int jj = 0; jj < 19; ++jj) {
      int j = jl + jj * 16;
      float v = 0.f;
      if (j < ND) {
        v = alpha * edge_feats[(size_t)e * ND + j] + (1.f - alpha) * acc[ei][jj];
        scp[ei] += v * ecWatt[j];
      }
      if (kc == 0) ef[(size_t)e * 304 + j] = v;
    }
  }
#pragma unroll
  for (int ei = 0; ei < 4; ++ei)
    for (int o = 8; o; o >>= 1) scp[ei] += __shfl_xor(scp[ei], o);
  if (lane == 0) {
#pragma unroll
    for (int ei = 0; ei < 4; ++ei) scores[e0 + w * 4 + ei] = scp[ei];
  }
}

// ---------------------------------------------------------------- k4a: softmax over 4096 edge scores
__global__ __launch_bounds__(1024) void k4a_softmax(const float* __restrict__ scores,
                                                    float* __restrict__ w) {
  __shared__ float red[16];
  __shared__ float red2[16];
  const int t = threadIdx.x, lane = t & 63, wv = t >> 6;
  float v[4];
  float mx = -1e30f;
#pragma unroll
  for (int u = 0; u < 4; ++u) {
    v[u] = scores[t + u * 1024];
    mx = fmaxf(mx, v[u]);
  }
  for (int o = 32; o; o >>= 1) mx = fmaxf(mx, __shfl_xor(mx, o));
  if (lane == 0) red[wv] = mx;
  __syncthreads();
  float m2 = red[0];
  for (int i = 1; i < 16; ++i) m2 = fmaxf(m2, red[i]);
  float s = 0.f;
#pragma unroll
  for (int u = 0; u < 4; ++u) {
    v[u] = expf(v[u] - m2);
    s += v[u];
  }
  for (int o = 32; o; o >>= 1) s += __shfl_xor(s, o);
  if (lane == 0) red2[wv] = s;
  __syncthreads();
  float S = 0.f;
  for (int i = 0; i < 16; ++i) S += red2[i];
  float inv = 1.f / S;
#pragma unroll
  for (int u = 0; u < 4; ++u) w[t + u * 1024] = v[u] * inv;
}

// ---------------------------------------------------------------- k4b: partial weighted pooling (64 edges/block)
__global__ __launch_bounds__(256) void k4b_pool(const float* __restrict__ ef,
                                                const float* __restrict__ w,
                                                float* __restrict__ partial) {
  const int b = blockIdx.x, t = threadIdx.x;
  const int e0 = b * 64;
  for (int j = t; j < 304; j += 256) {
    float acc = 0.f;
    for (int e = 0; e < 64; ++e) acc += w[e0 + e] * ef[(size_t)(e0 + e) * 304 + j];
    partial[b * 304 + j] = acc;
  }
}

// ---------------------------------------------------------------- k4c: final reduce + two matvecs -> 3 logits
__global__ __launch_bounds__(256) void k4c_final(const float* __restrict__ partial,
                                                 const float* __restrict__ ecWp,
                                                 const float* __restrict__ ecb,
                                                 const float* __restrict__ fcW,
                                                 const float* __restrict__ fcb,
                                                 float* __restrict__ out) {
  __shared__ float pooled[304];
  __shared__ float o[304];
  const int t = threadIdx.x;
  for (int j = t; j < 304; j += 256) {
    float acc = 0.f;
    for (int b = 0; b < 64; ++b) acc += partial[b * 304 + j];
    pooled[j] = acc;
  }
  __syncthreads();
  for (int j2 = t; j2 < ND; j2 += 256) {
    float acc = ecb[j2];
    for (int j = 0; j < ND; ++j) acc += pooled[j] * ecWp[j * ND + j2];
    o[j2] = acc;
  }
  __syncthreads();
  if (t < 3) {
    float acc = fcb[t];
    for (int j2 = 0; j2 < ND; ++j2) acc += o[j2] * fcW[j2 * 3 + t];
    out[t] = acc;
  }
}

// ----------------------------------------------------------------
extern "C" void kernel_launch(void* const* d_in, const int* in_sizes, int n_in,
                              void* d_out, int out_size, void* d_ws, size_t ws_size,
                              hipStream_t stream) {
  const float* X = (const float*)d_in[0];
  const float* EF = (const float*)d_in[1];
  const float* INC = (const float*)d_in[2];
  const float* WATT = (const float*)d_in[3];
  const float* WPROJ = (const float*)d_in[4];
  const float* ALPHA = (const float*)d_in[5];
  const float* ECATT = (const float*)d_in[6];
  const float* ECWP = (const float*)d_in[7];
  const float* ECB = (const float*)d_in[8];
  const float* FCW = (const float*)d_in[9];
  const float* FCB = (const float*)d_in[10];

  char* ws = (char*)d_ws;
  const bool big = (ws_size >= (size_t)68210688);

  f16* YT = (f16*)(ws);                  // 640*16384*2 = 20971520
  f16* X16 = (f16*)(ws + 20971520);      // 16384*320*2 = 10485760 (dead after k1b)
  f16* WT = (f16*)(ws + 31457280);       // 320*320*2   = 204800

  float *Z0, *Z1, *Z2, *Z3, *ef, *sc, *wv, *pp;
  if (big) {
    Z0 = (float*)(ws + 20971520);        // aliases X16 (dead)
    Z1 = (float*)(ws + 31662080);
    Z2 = (float*)(ws + 42147840);
    Z3 = (float*)(ws + 52633600);
    ef = (float*)(ws + 63119360);
    sc = (float*)(ws + 68100096);
    wv = (float*)(ws + 68116480);
    pp = (float*)(ws + 68132864);
  } else {
    Z0 = (float*)(ws + 20971520);        // aliases X16 (dead)
    Z1 = (float*)(ws + 31662080);
    Z2 = Z0; Z3 = Z1;                    // unused (nkb=2)
    ef = (float*)(ws + 42147840);
    sc = (float*)(ws + 47128576);
    wv = (float*)(ws + 47144960);
    pp = (float*)(ws + 47161344);
  }
  const int nkb = big ? 4 : 2;

  hipLaunchKernelGGL(k0_wt, dim3(400), dim3(256), 0, stream, WATT, WT);
  hipLaunchKernelGGL(k1a_xprep, dim3(256), dim3(256), 0, stream, X, X16, YT);
  hipLaunchKernelGGL(k1b_xat, dim3(256), dim3(512), 0, stream, WT, X16, YT);
  if (big) {
    hipLaunchKernelGGL((k2_bigmm<4>), dim3(256), dim3(256), 0, stream, INC, YT,
                       Z0, Z1, Z2, Z3);
  } else {
    hipLaunchKernelGGL((k2_bigmm<2>), dim3(128), dim3(256), 0, stream, INC, YT,
                       Z0, Z1, Z2, Z3);
  }
  hipLaunchKernelGGL(k3_edge, dim3(256), dim3(256), 0, stream, Z0, Z1, Z2, Z3,
                     nkb, EF, WPROJ, ALPHA, ECATT, ef, sc);
  hipLaunchKernelGGL(k4a_softmax, dim3(1), dim3(1024), 0, stream, sc, wv);
  hipLaunchKernelGGL(k4b_pool, dim3(64), dim3(256), 0, stream, ef, wv, pp);
  hipLaunchKernelGGL(k4c_final, dim3(1), dim3(256), 0, stream, pp, ECWP, ECB, FCW,
                     FCB, (float*)d_out);
}

// Round 8
// 293.821 us; speedup vs baseline: 1.6103x; 1.0939x over previous
//
#include <hip/hip_runtime.h>
#include <math.h>

typedef _Float16 f16;
typedef _Float16 f16x8 __attribute__((ext_vector_type(8)));
typedef _Float16 f16x4 __attribute__((ext_vector_type(4)));
typedef __fp16 fp16x2 __attribute__((ext_vector_type(2)));
typedef float f32x4 __attribute__((ext_vector_type(4)));
typedef float f32x16 __attribute__((ext_vector_type(16)));

#define NM 16384   // nodes (K of big GEMM)
#define NE 4096    // hyperedges
#define ND 300     // feature dim
#define DP 320     // padded feature dim
#define JT 640     // 2*DP columns of Z
#define PS 2621440 // per-partial f16 elements (4096*640)

__device__ __forceinline__ int swz(int r) { return (r ^ (r >> 2)) & 3; }

#define GLOAD_LDS16(gsrc, ldst)                                              \
  __builtin_amdgcn_global_load_lds(                                          \
      (__attribute__((address_space(1))) void*)(gsrc),                       \
      (__attribute__((address_space(3))) void*)(ldst), 16, 0, 0)

// ---------------------------------------------------------------- k0: W_att^T -> fp16 (DPxDP)
__global__ void k0_wt(const float* __restrict__ Watt, f16* __restrict__ WT) {
  int idx = blockIdx.x * 256 + threadIdx.x;
  if (idx >= DP * DP) return;
  int j = idx / DP, d = idx % DP;
  float v = (j < ND && d < ND) ? Watt[d * ND + j] : 0.f;
  WT[(size_t)j * DP + d] = (f16)v;
}

// ---------------------------------------------------------------- k1a: X -> X16 [m][DP] and YT rows 320..639 (X^T)
__global__ __launch_bounds__(256) void k1a_xprep(const float* __restrict__ X,
                                                 f16* __restrict__ X16,
                                                 f16* __restrict__ YT) {
  __shared__ f16 tile[64][324];
  int m0 = blockIdx.x * 64;
  for (int idx = threadIdx.x; idx < 64 * 80; idx += 256) {
    int m = idx / 80, q = idx % 80;
    int d = q * 4;
    float4 v = make_float4(0.f, 0.f, 0.f, 0.f);
    if (d < ND) v = *(const float4*)(X + (size_t)(m0 + m) * ND + d);
    f16x4 hv;
    hv[0] = (f16)v.x; hv[1] = (f16)v.y; hv[2] = (f16)v.z; hv[3] = (f16)v.w;
    tile[m][d] = hv[0]; tile[m][d + 1] = hv[1];
    tile[m][d + 2] = hv[2]; tile[m][d + 3] = hv[3];
    *(f16x4*)(X16 + (size_t)(m0 + m) * DP + d) = hv;
  }
  __syncthreads();
  for (int idx = threadIdx.x; idx < DP * 8; idx += 256) {
    int d = idx >> 3, part = idx & 7;
    f16x8 hv;
#pragma unroll
    for (int i = 0; i < 8; ++i) hv[i] = tile[part * 8 + i][d];
    *(f16x8*)(YT + (size_t)(DP + d) * NM + m0 + part * 8) = hv;
  }
}

// ---------------------------------------------------------------- k1b: YT rows 0..319 = W^T @ X^T (fp16 MFMA)
__global__ __launch_bounds__(512, 2) void k1b_xat(const f16* __restrict__ WT,
                                                  const f16* __restrict__ X16,
                                                  f16* __restrict__ YT) {
  __shared__ __align__(16) char lds[49152];
  const int t = threadIdx.x, lane = t & 63, wid = t >> 6;
  const int m0 = blockIdx.x * 64;
  const int row = lane & 15, g = lane >> 4;
  const int wj = wid & 3, wm = wid >> 2;
  int aoff[5], boff[2];
#pragma unroll
  for (int f = 0; f < 5; ++f) {
    int jr = wj * 80 + f * 16 + row;
    aoff[f] = jr * 64 + ((g ^ swz(jr)) << 4);
  }
#pragma unroll
  for (int fm = 0; fm < 2; ++fm) {
    int mr = wm * 32 + fm * 16 + row;
    boff[fm] = mr * 64 + ((g ^ swz(mr)) << 4);
  }
  f32x4 acc[5][2];
#pragma unroll
  for (int f = 0; f < 5; ++f)
#pragma unroll
    for (int fm = 0; fm < 2; ++fm)
#pragma unroll
      for (int r = 0; r < 4; ++r) acc[f][fm][r] = 0.f;

  auto stage = [&](int buf, int ks) {
    int k0 = ks * 32;
    char* A = lds + buf * 20480;
    char* B = lds + 40960 + buf * 4096;
    for (int c = wid; c < 24; c += 8) {
      if (c < 20) {
        int j = c * 16 + (lane >> 2), gg = lane & 3;
        GLOAD_LDS16(WT + (size_t)j * DP + k0 + 8 * (gg ^ swz(j)), A + c * 1024);
      } else {
        int cb = c - 20;
        int m = cb * 16 + (lane >> 2), gg = lane & 3;
        GLOAD_LDS16(X16 + (size_t)(m0 + m) * DP + k0 + 8 * (gg ^ swz(m)),
                    B + cb * 1024);
      }
    }
  };
  stage(0, 0);
  __syncthreads();
  for (int ks = 0; ks < 10; ++ks) {
    int cur = ks & 1;
    if (ks + 1 < 10) stage(cur ^ 1, ks + 1);
    const char* A = lds + cur * 20480;
    const char* B = lds + 40960 + cur * 4096;
    f16x8 b0 = *(const f16x8*)(B + boff[0]);
    f16x8 b1 = *(const f16x8*)(B + boff[1]);
#pragma unroll
    for (int f = 0; f < 5; ++f) {
      f16x8 a = *(const f16x8*)(A + aoff[f]);
      acc[f][0] = __builtin_amdgcn_mfma_f32_16x16x32_f16(a, b0, acc[f][0], 0, 0, 0);
      acc[f][1] = __builtin_amdgcn_mfma_f32_16x16x32_f16(a, b1, acc[f][1], 0, 0, 0);
    }
    __syncthreads();
  }
#pragma unroll
  for (int f = 0; f < 5; ++f)
#pragma unroll
    for (int fm = 0; fm < 2; ++fm)
#pragma unroll
      for (int r = 0; r < 4; ++r) {
        int j = wj * 80 + f * 16 + g * 4 + r;
        int m = m0 + wm * 32 + fm * 16 + row;
        YT[(size_t)j * NM + m] = (f16)acc[f][fm][r];
      }
}

// ---------------------------------------------------------------- k2 v7: Z = inc^T @ Y, 32x32x16 MFMA
// block 128e x 320j x BK32, 4 waves (2e x 2j), wave 64e x 160j (Ma=2,Nb=5).
// grid 512 = 32 eb x 2 jn x 8 kb, xcd = kb (YT slab shared per XCD, inc disjoint).
// LDS 56 KB ring-2 (64-B rows, 2-bit slot XOR swizzle) -> 2 blocks/CU = 2 waves/SIMD.
// Partials: 8 x f16 (4096x640). Counted vmcnt: 21/step (16 A-loads + 5 B-dmas).
// LDS: Bbuf[2] @ 0/20480 (320 rows x 64B); Abuf[2] @ 40960/49152 (128 rows x 64B)
#define K2WAIT(N) asm volatile("s_waitcnt vmcnt(" #N ") lgkmcnt(0)" ::: "memory")
#define K2BAR()                                        \
  do {                                                 \
    asm volatile("" ::: "memory");                     \
    __builtin_amdgcn_s_barrier();                      \
    asm volatile("" ::: "memory");                     \
  } while (0)

__global__ __launch_bounds__(256, 2) void k2_bigmm(const float* __restrict__ inc,
                                                   const f16* __restrict__ YT,
                                                   f16* __restrict__ Zp) {
  constexpr int STEPS = 64;  // 2048 k / 32
  __shared__ __align__(16) char lds[57344];
  const int t = threadIdx.x, lane = t & 63, wid = t >> 6;
  const int bx = blockIdx.x;
  const int kb = bx & 7, y = bx >> 3;
  const int eb = y & 31, jn = y >> 5;
  const int e0 = eb * 128, j0 = jn * 320;
  const size_t kbase = (size_t)kb * 2048;
  f16* __restrict__ Zout = Zp + (size_t)kb * PS;

  const int we = wid >> 1, wj = wid & 1;
  const int l31 = lane & 31, oct = lane >> 5;
  int sl[2];
#pragma unroll
  for (int kk = 0; kk < 2; ++kk)
    sl[kk] = (((kk * 2 + oct) ^ ((l31 >> 1) & 3)) & 3) << 4;
  const int arow = (we * 64 + l31) * 64;   // +2048 for me=1 (32 rows)
  const int brow = (wj * 160 + l31) * 64;  // +f*2048 (32 rows)
  // A staging: thread = (ep = t&63) x (kq = t>>6); e's {ep, ep+64}, k-chunk kq
  const int ep = t & 63, kq = t >> 6;
  const int sA = (kq ^ ((ep >> 1) & 3)) & 3;
  const int wa0 = 40960 + ep * 64 + sA * 16;
  const int wa1 = 40960 + (ep + 64) * 64 + sA * 16;
  const float* pA = inc + (kbase + kq * 8) * NE + e0 + ep;
  // B dma: per-lane pre-swizzled global source
  const int br = wid * 80 + (lane >> 2);
  const f16* pB = YT + (size_t)(j0 + br) * NM + kbase +
                  8 * ((lane & 3) ^ ((lane >> 3) & 3));

  float rAx[8], rAy[8], rBx[8], rBy[8];
  f32x16 acc[2][5];
#pragma unroll
  for (int me = 0; me < 2; ++me)
#pragma unroll
    for (int f = 0; f < 5; ++f)
#pragma unroll
      for (int r = 0; r < 16; ++r) acc[me][f][r] = 0.f;

#define LOADA(RX, RY)                                                          \
  {                                                                            \
    _Pragma("unroll") for (int i = 0; i < 8; ++i) {                            \
      RX[i] = pA[(size_t)i * NE];                                              \
      RY[i] = pA[(size_t)i * NE + 64];                                         \
    }                                                                          \
    pA += (size_t)32 * NE;                                                     \
  }
#define DMAB(S)                                                                \
  {                                                                            \
    _Pragma("unroll") for (int i = 0; i < 5; ++i) {                            \
      GLOAD_LDS16(pB + (size_t)(i * 16) * NM,                                  \
                  lds + (S)*20480 + wid * 5120 + i * 1024);                    \
    }                                                                          \
    pB += 32;                                                                  \
  }
#define WRITEA(RX, RY, S)                                                      \
  {                                                                            \
    union { fp16x2 h; uint32_t u; } ux_[4], uy_[4];                            \
    _Pragma("unroll") for (int z = 0; z < 4; ++z) {                            \
      ux_[z].h = __builtin_amdgcn_cvt_pkrtz(RX[2 * z], RX[2 * z + 1]);         \
      uy_[z].h = __builtin_amdgcn_cvt_pkrtz(RY[2 * z], RY[2 * z + 1]);         \
    }                                                                          \
    *(uint4*)(lds + wa0 + (S)*8192) =                                          \
        make_uint4(ux_[0].u, ux_[1].u, ux_[2].u, ux_[3].u);                    \
    *(uint4*)(lds + wa1 + (S)*8192) =                                          \
        make_uint4(uy_[0].u, uy_[1].u, uy_[2].u, uy_[3].u);                    \
  }
#define COMPUTE(S)                                                             \
  {                                                                            \
    __builtin_amdgcn_s_setprio(1);                                             \
    _Pragma("unroll") for (int kk = 0; kk < 2; ++kk) {                         \
      f16x8 a0_ = *(const f16x8*)(lds + 40960 + (S)*8192 + arow + sl[kk]);     \
      f16x8 a1_ = *(const f16x8*)(lds + 40960 + (S)*8192 + arow + 2048 + sl[kk]); \
      _Pragma("unroll") for (int f = 0; f < 5; ++f) {                          \
        f16x8 b_ = *(const f16x8*)(lds + (S)*20480 + brow + f * 2048 + sl[kk]); \
        acc[0][f] = __builtin_amdgcn_mfma_f32_32x32x16_f16(a0_, b_, acc[0][f], 0, 0, 0); \
        acc[1][f] = __builtin_amdgcn_mfma_f32_32x32x16_f16(a1_, b_, acc[1][f], 0, 0, 0); \
      }                                                                        \
    }                                                                          \
    __builtin_amdgcn_s_setprio(0);                                             \
  }

  // prologue
  LOADA(rAx, rAy);           // A(0)
  DMAB(0);                   // B(0)
  WRITEA(rAx, rAy, 0);       // implicit wait A(0) (vmcnt 5)
  LOADA(rAx, rAy);           // A(1)
  DMAB(1);                   // B(1); outstanding = 26
  K2WAIT(21);                // drain B(0)
  K2BAR();

  for (int tt = 0; tt < STEPS - 2; ++tt) {
    COMPUTE(tt & 1);
    K2BAR();
    WRITEA(rAx, rAy, (tt + 1) & 1);  // implicit wait A(tt+1)
    LOADA(rAx, rAy);                 // A(tt+2)
    DMAB(tt & 1);                    // B(tt+2)
    K2WAIT(21);                      // drain B(tt+1)
    K2BAR();
  }
  COMPUTE(0);  // (STEPS-2)&1 == 0
  K2BAR();
  WRITEA(rAx, rAy, 1);  // A(STEPS-1)
  K2WAIT(0);            // drain B(STEPS-1)
  K2BAR();
  COMPUTE(1);

  // epilogue: f16 partial store (C/D: col=lane&31, row=(r&3)+8*(r>>2)+4*oct)
#pragma unroll
  for (int me = 0; me < 2; ++me)
#pragma unroll
    for (int f = 0; f < 5; ++f) {
      int jg = j0 + wj * 160 + f * 32 + l31;
      int ebase = e0 + we * 64 + me * 32 + 4 * oct;
#pragma unroll
      for (int r = 0; r < 16; ++r) {
        int eg = ebase + (r & 3) + 8 * (r >> 2);
        Zout[(size_t)eg * JT + jg] = (f16)acc[me][f][r];
      }
    }
#undef LOADA
#undef DMAB
#undef WRITEA
#undef COMPUTE
}

// ---------------------------------------------------------------- k3 v4: sums 8 f16 partials + softmax + projection
__global__ __launch_bounds__(256) void k3_edge(const f16* __restrict__ Zp,
                                               const float* __restrict__ edge_feats,
                                               const float* __restrict__ Wproj,
                                               const float* __restrict__ alphaP,
                                               const float* __restrict__ ecWatt,
                                               float* __restrict__ ef,
                                               float* __restrict__ scores) {
  __shared__ float efw[16][304];
  const int t = threadIdx.x, lane = t & 63, w = t >> 6;
  const int e0 = blockIdx.x * 16;
  // phase 1: feature softmax, weight ef0
  for (int el = 0; el < 4; ++el) {
    int e = e0 + w * 4 + el;
    const size_t ro = (size_t)e * JT;
    float p[5];
    float mx = -1e30f;
#pragma unroll
    for (int u = 0; u < 5; ++u) {
      int d = u * 64 + lane;
      float zv = -1e30f;
      if (d < ND) {
        zv = 0.f;
#pragma unroll
        for (int i = 0; i < 8; ++i) zv += (float)Zp[(size_t)i * PS + ro + d];
      }
      p[u] = zv;
      mx = fmaxf(mx, p[u]);
    }
    for (int o = 32; o; o >>= 1) mx = fmaxf(mx, __shfl_xor(mx, o));
    float s = 0.f;
#pragma unroll
    for (int u = 0; u < 5; ++u) {
      int d = u * 64 + lane;
      float pe = (d < ND) ? expf(p[u] - mx) : 0.f;
      p[u] = pe;
      s += pe;
    }
    for (int o = 32; o; o >>= 1) s += __shfl_xor(s, o);
    float inv = 1.f / s;
#pragma unroll
    for (int u = 0; u < 5; ++u) {
      int d = u * 64 + lane;
      if (d < 304) {
        float rv = 0.f;
        if (d < ND) {
#pragma unroll
          for (int i = 0; i < 8; ++i) rv += (float)Zp[(size_t)i * PS + ro + DP + d];
          rv *= p[u] * inv;
        }
        efw[w * 4 + el][d] = rv;
      }
    }
  }
  __syncthreads();
  // phase 2: register-blocked (ef0*attn) @ W_proj + residual + scores
  const int jl = lane & 15, kc = lane >> 4;
  const float alpha = alphaP[0];
  float acc[4][19];
#pragma unroll
  for (int ei = 0; ei < 4; ++ei)
#pragma unroll
    for (int jj = 0; jj < 19; ++jj) acc[ei][jj] = 0.f;
  const int d0 = kc * 75;
  const float* efw0 = &efw[w * 4 + 0][0];
  const float* efw1 = &efw[w * 4 + 1][0];
  const float* efw2 = &efw[w * 4 + 2][0];
  const float* efw3 = &efw[w * 4 + 3][0];
  for (int dd = 0; dd < 75; ++dd) {
    int d = d0 + dd;
    const float* wr = Wproj + (size_t)d * ND + jl;
    float w0 = efw0[d], w1 = efw1[d], w2 = efw2[d], w3 = efw3[d];
#pragma unroll
    for (int jj = 0; jj < 19; ++jj) {
      int j = jl + jj * 16;
      float wv = (j < ND) ? wr[jj * 16] : 0.f;
      acc[0][jj] += w0 * wv;
      acc[1][jj] += w1 * wv;
      acc[2][jj] += w2 * wv;
      acc[3][jj] += w3 * wv;
    }
  }
#pragma unroll
  for (int ei = 0; ei < 4; ++ei)
#pragma unroll
    for (int jj = 0; jj < 19; ++jj) {
      acc[ei][jj] += __shfl_xor(acc[ei][jj], 16);
      acc[ei][jj] += __shfl_xor(acc[ei][jj], 32);
    }
  float scp[4] = {0.f, 0.f, 0.f, 0.f};
#pragma unroll
  for (int ei = 0; ei < 4; ++ei) {
    int e = e0 + w * 4 + ei;
#pragma unroll
    for (int jj = 0; jj < 19; ++jj) {
      int j = jl + jj * 16;
      float v = 0.f;
      if (j < ND) {
        v = alpha * edge_feats[(size_t)e * ND + j] + (1.f - alpha) * acc[ei][jj];
        scp[ei] += v * ecWatt[j];
      }
      if (kc == 0) ef[(size_t)e * 304 + j] = v;
    }
  }
#pragma unroll
  for (int ei = 0; ei < 4; ++ei)
    for (int o = 8; o; o >>= 1) scp[ei] += __shfl_xor(scp[ei], o);
  if (lane == 0) {
#pragma unroll
    for (int ei = 0; ei < 4; ++ei) scores[e0 + w * 4 + ei] = scp[ei];
  }
}

// ---------------------------------------------------------------- k4a: softmax over 4096 edge scores
__global__ __launch_bounds__(1024) void k4a_softmax(const float* __restrict__ scores,
                                                    float* __restrict__ w) {
  __shared__ float red[16];
  __shared__ float red2[16];
  const int t = threadIdx.x, lane = t & 63, wv = t >> 6;
  float v[4];
  float mx = -1e30f;
#pragma unroll
  for (int u = 0; u < 4; ++u) {
    v[u] = scores[t + u * 1024];
    mx = fmaxf(mx, v[u]);
  }
  for (int o = 32; o; o >>= 1) mx = fmaxf(mx, __shfl_xor(mx, o));
  if (lane == 0) red[wv] = mx;
  __syncthreads();
  float m2 = red[0];
  for (int i = 1; i < 16; ++i) m2 = fmaxf(m2, red[i]);
  float s = 0.f;
#pragma unroll
  for (int u = 0; u < 4; ++u) {
    v[u] = expf(v[u] - m2);
    s += v[u];
  }
  for (int o = 32; o; o >>= 1) s += __shfl_xor(s, o);
  if (lane == 0) red2[wv] = s;
  __syncthreads();
  float S = 0.f;
  for (int i = 0; i < 16; ++i) S += red2[i];
  float inv = 1.f / S;
#pragma unroll
  for (int u = 0; u < 4; ++u) w[t + u * 1024] = v[u] * inv;
}

// ---------------------------------------------------------------- k4b: partial weighted pooling (64 edges/block)
__global__ __launch_bounds__(256) void k4b_pool(const float* __restrict__ ef,
                                                const float* __restrict__ w,
                                                float* __restrict__ partial) {
  const int b = blockIdx.x, t = threadIdx.x;
  const int e0 = b * 64;
  for (int j = t; j < 304; j += 256) {
    float acc = 0.f;
    for (int e = 0; e < 64; ++e) acc += w[e0 + e] * ef[(size_t)(e0 + e) * 304 + j];
    partial[b * 304 + j] = acc;
  }
}

// ---------------------------------------------------------------- k4c: final reduce + two matvecs -> 3 logits
__global__ __launch_bounds__(256) void k4c_final(const float* __restrict__ partial,
                                                 const float* __restrict__ ecWp,
                                                 const float* __restrict__ ecb,
                                                 const float* __restrict__ fcW,
                                                 const float* __restrict__ fcb,
                                                 float* __restrict__ out) {
  __shared__ float pooled[304];
  __shared__ float o[304];
  const int t = threadIdx.x;
  for (int j = t; j < 304; j += 256) {
    float acc = 0.f;
    for (int b = 0; b < 64; ++b) acc += partial[b * 304 + j];
    pooled[j] = acc;
  }
  __syncthreads();
  for (int j2 = t; j2 < ND; j2 += 256) {
    float acc = ecb[j2];
    for (int j = 0; j < ND; ++j) acc += pooled[j] * ecWp[j * ND + j2];
    o[j2] = acc;
  }
  __syncthreads();
  if (t < 3) {
    float acc = fcb[t];
    for (int j2 = 0; j2 < ND; ++j2) acc += o[j2] * fcW[j2 * 3 + t];
    out[t] = acc;
  }
}

// ----------------------------------------------------------------
extern "C" void kernel_launch(void* const* d_in, const int* in_sizes, int n_in,
                              void* d_out, int out_size, void* d_ws, size_t ws_size,
                              hipStream_t stream) {
  const float* X = (const float*)d_in[0];
  const float* EF = (const float*)d_in[1];
  const float* INC = (const float*)d_in[2];
  const float* WATT = (const float*)d_in[3];
  const float* WPROJ = (const float*)d_in[4];
  const float* ALPHA = (const float*)d_in[5];
  const float* ECATT = (const float*)d_in[6];
  const float* ECWP = (const float*)d_in[7];
  const float* ECB = (const float*)d_in[8];
  const float* FCW = (const float*)d_in[9];
  const float* FCB = (const float*)d_in[10];

  char* ws = (char*)d_ws;
  // layout (total 68,210,688 B — proven available):
  f16* YT = (f16*)(ws);                  // [0, 20971520)
  f16* X16 = (f16*)(ws + 20971520);      // [20971520, 31457280) dead after k1b
  f16* Zp = (f16*)(ws + 20971520);       // 8 x 5242880 B -> [20971520, 62914560)
  f16* WT = (f16*)(ws + 62914560);       // [62914560, 63119360) dead after k1b
  float* ef = (float*)(ws + 63119360);   // [63119360, 68100096)
  float* sc = (float*)(ws + 68100096);
  float* wv = (float*)(ws + 68116480);
  float* pp = (float*)(ws + 68132864);   // ends 68210688

  hipLaunchKernelGGL(k0_wt, dim3(400), dim3(256), 0, stream, WATT, WT);
  hipLaunchKernelGGL(k1a_xprep, dim3(256), dim3(256), 0, stream, X, X16, YT);
  hipLaunchKernelGGL(k1b_xat, dim3(256), dim3(512), 0, stream, WT, X16, YT);
  hipLaunchKernelGGL(k2_bigmm, dim3(512), dim3(256), 0, stream, INC, YT, Zp);
  hipLaunchKernelGGL(k3_edge, dim3(256), dim3(256), 0, stream, Zp, EF, WPROJ,
                     ALPHA, ECATT, ef, sc);
  hipLaunchKernelGGL(k4a_softmax, dim3(1), dim3(1024), 0, stream, sc, wv);
  hipLaunchKernelGGL(k4b_pool, dim3(64), dim3(256), 0, stream, ef, wv, pp);
  hipLaunchKernelGGL(k4c_final, dim3(1), dim3(256), 0, stream, pp, ECWP, ECB, FCW,
                     FCB, (float*)d_out);
}

// Round 9
// 252.118 us; speedup vs baseline: 1.8767x; 1.1654x over previous
//
#include <hip/hip_runtime.h>
#include <math.h>

typedef _Float16 f16;
typedef _Float16 f16x8 __attribute__((ext_vector_type(8)));
typedef _Float16 f16x4 __attribute__((ext_vector_type(4)));
typedef __fp16 fp16x2 __attribute__((ext_vector_type(2)));
typedef float f32x4 __attribute__((ext_vector_type(4)));
typedef float f32x16 __attribute__((ext_vector_type(16)));

#define NM 16384    // nodes (K of big GEMM)
#define NE 4096     // hyperedges
#define ND 300      // feature dim
#define DP 320      // padded feature dim
#define PS 1310720  // per-partial f16 elements (4096*320)

__device__ __forceinline__ int swz(int r) { return (r ^ (r >> 2)) & 3; }

#define GLOAD_LDS16(gsrc, ldst)                                              \
  __builtin_amdgcn_global_load_lds(                                          \
      (__attribute__((address_space(1))) void*)(gsrc),                       \
      (__attribute__((address_space(3))) void*)(ldst), 16, 0, 0)

// ---------------------------------------------------------------- k0: W_att^T -> fp16 (DPxDP)
__global__ void k0_wt(const float* __restrict__ Watt, f16* __restrict__ WT) {
  int idx = blockIdx.x * 256 + threadIdx.x;
  if (idx >= DP * DP) return;
  int j = idx / DP, d = idx % DP;
  float v = (j < ND && d < ND) ? Watt[d * ND + j] : 0.f;
  WT[(size_t)j * DP + d] = (f16)v;
}

// ---------------------------------------------------------------- k1a: X -> XT rows 0..319 (X^T, f16, zero-padded)
__global__ __launch_bounds__(256) void k1a_xprep(const float* __restrict__ X,
                                                 f16* __restrict__ XT) {
  __shared__ f16 tile[64][324];
  int m0 = blockIdx.x * 64;
  for (int idx = threadIdx.x; idx < 64 * 80; idx += 256) {
    int m = idx / 80, q = idx % 80;
    int d = q * 4;
    float4 v = make_float4(0.f, 0.f, 0.f, 0.f);
    if (d < ND) v = *(const float4*)(X + (size_t)(m0 + m) * ND + d);
    tile[m][d] = (f16)v.x; tile[m][d + 1] = (f16)v.y;
    tile[m][d + 2] = (f16)v.z; tile[m][d + 3] = (f16)v.w;
  }
  __syncthreads();
  for (int idx = threadIdx.x; idx < DP * 8; idx += 256) {
    int d = idx >> 3, part = idx & 7;
    f16x8 hv;
#pragma unroll
    for (int i = 0; i < 8; ++i) hv[i] = tile[part * 8 + i][d];
    *(f16x8*)(XT + (size_t)d * NM + m0 + part * 8) = hv;
  }
}

// ---------------------------------------------------------------- k2 v8: EF0 = inc^T @ X, 32x32x16 MFMA
// block 128e x 320j x BK32, 4 waves (2e x 2j), wave 64e x 160j (Ma=2,Nb=5).
// grid 512 = 32 eb x 16 kb, xcd = kb&7 (XT slab per-XCD L2, inc disjoint).
// LDS 56 KB ring-2 -> 2 blocks/CU. Partials: 16 x f16 (4096x320).
// LDS: Bbuf[2] @ 0/20480 (320 rows x 64B); Abuf[2] @ 40960/49152 (128 rows x 64B)
#define K2WAIT(N) asm volatile("s_waitcnt vmcnt(" #N ") lgkmcnt(0)" ::: "memory")
#define K2BAR()                                        \
  do {                                                 \
    asm volatile("" ::: "memory");                     \
    __builtin_amdgcn_s_barrier();                      \
    asm volatile("" ::: "memory");                     \
  } while (0)

__global__ __launch_bounds__(256, 2) void k2_bigmm(const float* __restrict__ inc,
                                                   const f16* __restrict__ XT,
                                                   f16* __restrict__ Zp) {
  constexpr int STEPS = 32;  // 1024 k / 32
  __shared__ __align__(16) char lds[57344];
  const int t = threadIdx.x, lane = t & 63, wid = t >> 6;
  const int bx = blockIdx.x;
  const int kb = (bx & 7) | (((bx >> 3) & 1) << 3);
  const int eb = bx >> 4;
  const int e0 = eb * 128;
  const size_t kbase = (size_t)kb * 1024;
  f16* __restrict__ Zout = Zp + (size_t)kb * PS;

  const int we = wid >> 1, wj = wid & 1;
  const int l31 = lane & 31, oct = lane >> 5;
  int sl[2];
#pragma unroll
  for (int kk = 0; kk < 2; ++kk)
    sl[kk] = (((kk * 2 + oct) ^ ((l31 >> 1) & 3)) & 3) << 4;
  const int arow = (we * 64 + l31) * 64;
  const int brow = (wj * 160 + l31) * 64;
  // A staging: thread = (ep = t&63) x (kq = t>>6)
  const int ep = t & 63, kq = t >> 6;
  const int sA = (kq ^ ((ep >> 1) & 3)) & 3;
  const int wa0 = 40960 + ep * 64 + sA * 16;
  const int wa1 = 40960 + (ep + 64) * 64 + sA * 16;
  const float* pA = inc + (kbase + kq * 8) * NE + e0 + ep;
  // B dma: per-lane pre-swizzled global source
  const int br = wid * 80 + (lane >> 2);
  const f16* pB = XT + (size_t)br * NM + kbase + 8 * ((lane & 3) ^ ((lane >> 3) & 3));

  float rAx[8], rAy[8];
  f32x16 acc[2][5];
#pragma unroll
  for (int me = 0; me < 2; ++me)
#pragma unroll
    for (int f = 0; f < 5; ++f)
#pragma unroll
      for (int r = 0; r < 16; ++r) acc[me][f][r] = 0.f;

#define LOADA(RX, RY)                                                          \
  {                                                                            \
    _Pragma("unroll") for (int i = 0; i < 8; ++i) {                            \
      RX[i] = pA[(size_t)i * NE];                                              \
      RY[i] = pA[(size_t)i * NE + 64];                                         \
    }                                                                          \
    pA += (size_t)32 * NE;                                                     \
  }
#define DMAB(S)                                                                \
  {                                                                            \
    _Pragma("unroll") for (int i = 0; i < 5; ++i) {                            \
      GLOAD_LDS16(pB + (size_t)(i * 16) * NM,                                  \
                  lds + (S)*20480 + wid * 5120 + i * 1024);                    \
    }                                                                          \
    pB += 32;                                                                  \
  }
#define WRITEA(RX, RY, S)                                                      \
  {                                                                            \
    union { fp16x2 h; uint32_t u; } ux_[4], uy_[4];                            \
    _Pragma("unroll") for (int z = 0; z < 4; ++z) {                            \
      ux_[z].h = __builtin_amdgcn_cvt_pkrtz(RX[2 * z], RX[2 * z + 1]);         \
      uy_[z].h = __builtin_amdgcn_cvt_pkrtz(RY[2 * z], RY[2 * z + 1]);         \
    }                                                                          \
    *(uint4*)(lds + wa0 + (S)*8192) =                                          \
        make_uint4(ux_[0].u, ux_[1].u, ux_[2].u, ux_[3].u);                    \
    *(uint4*)(lds + wa1 + (S)*8192) =                                          \
        make_uint4(uy_[0].u, uy_[1].u, uy_[2].u, uy_[3].u);                    \
  }
#define COMPUTE(S)                                                             \
  {                                                                            \
    __builtin_amdgcn_s_setprio(1);                                             \
    _Pragma("unroll") for (int kk = 0; kk < 2; ++kk) {                         \
      f16x8 a0_ = *(const f16x8*)(lds + 40960 + (S)*8192 + arow + sl[kk]);     \
      f16x8 a1_ = *(const f16x8*)(lds + 40960 + (S)*8192 + arow + 2048 + sl[kk]); \
      _Pragma("unroll") for (int f = 0; f < 5; ++f) {                          \
        f16x8 b_ = *(const f16x8*)(lds + (S)*20480 + brow + f * 2048 + sl[kk]); \
        acc[0][f] = __builtin_amdgcn_mfma_f32_32x32x16_f16(a0_, b_, acc[0][f], 0, 0, 0); \
        acc[1][f] = __builtin_amdgcn_mfma_f32_32x32x16_f16(a1_, b_, acc[1][f], 0, 0, 0); \
      }                                                                        \
    }                                                                          \
    __builtin_amdgcn_s_setprio(0);                                             \
  }

  // prologue
  LOADA(rAx, rAy);           // A(0)
  DMAB(0);                   // B(0)
  WRITEA(rAx, rAy, 0);       // implicit wait A(0)
  LOADA(rAx, rAy);           // A(1)
  DMAB(1);                   // B(1)
  K2WAIT(21);                // drain B(0)
  K2BAR();

  for (int tt = 0; tt < STEPS - 2; ++tt) {
    COMPUTE(tt & 1);
    K2BAR();
    WRITEA(rAx, rAy, (tt + 1) & 1);  // implicit wait A(tt+1)
    LOADA(rAx, rAy);                 // A(tt+2)
    DMAB(tt & 1);                    // B(tt+2)
    K2WAIT(21);                      // drain B(tt+1)
    K2BAR();
  }
  COMPUTE(0);  // (STEPS-2)&1 == 0
  K2BAR();
  WRITEA(rAx, rAy, 1);  // A(STEPS-1)
  K2WAIT(0);            // drain B(STEPS-1)
  K2BAR();
  COMPUTE(1);

  // epilogue: f16 partial store (C/D: col=lane&31 -> j, row=(r&3)+8*(r>>2)+4*oct -> e)
#pragma unroll
  for (int me = 0; me < 2; ++me)
#pragma unroll
    for (int f = 0; f < 5; ++f) {
      int jg = wj * 160 + f * 32 + l31;
      int ebase = e0 + we * 64 + me * 32 + 4 * oct;
#pragma unroll
      for (int r = 0; r < 16; ++r) {
        int eg = ebase + (r & 3) + 8 * (r >> 2);
        Zout[(size_t)eg * DP + jg] = (f16)acc[me][f][r];
      }
    }
#undef LOADA
#undef DMAB
#undef WRITEA
}

// ---------------------------------------------------------------- k2s: sum 16 f16 partials -> EF0 (f16)
__global__ __launch_bounds__(256) void k2s_sum(const f16* __restrict__ Zp,
                                               f16* __restrict__ EF0) {
  const int idx = (blockIdx.x * 256 + threadIdx.x) * 4;
  float s0 = 0.f, s1 = 0.f, s2 = 0.f, s3 = 0.f;
#pragma unroll
  for (int i = 0; i < 16; ++i) {
    f16x4 v = *(const f16x4*)(Zp + (size_t)i * PS + idx);
    s0 += (float)v[0]; s1 += (float)v[1]; s2 += (float)v[2]; s3 += (float)v[3];
  }
  f16x4 o;
  o[0] = (f16)s0; o[1] = (f16)s1; o[2] = (f16)s2; o[3] = (f16)s3;
  *(f16x4*)(EF0 + idx) = o;
}

// ---------------------------------------------------------------- k2b: att = EF0 @ W_att (f32 out), 32 blocks
// block 128e x 320j, K=320 (10 steps of 32). Both operands gload_lds-staged.
// Same LDS layout / COMPUTE as k2.
__global__ __launch_bounds__(256, 1) void k2b_att(const f16* __restrict__ EF0,
                                                  const f16* __restrict__ WT,
                                                  float* __restrict__ att) {
  constexpr int STEPS = 10;
  __shared__ __align__(16) char lds[57344];
  const int t = threadIdx.x, lane = t & 63, wid = t >> 6;
  const int e0 = blockIdx.x * 128;
  const int we = wid >> 1, wj = wid & 1;
  const int l31 = lane & 31, oct = lane >> 5;
  int sl[2];
#pragma unroll
  for (int kk = 0; kk < 2; ++kk)
    sl[kk] = (((kk * 2 + oct) ^ ((l31 >> 1) & 3)) & 3) << 4;
  const int arow = (we * 64 + l31) * 64;
  const int brow = (wj * 160 + l31) * 64;
  const int srcsw = 8 * ((lane & 3) ^ ((lane >> 3) & 3));
  const f16* pA = EF0 + (size_t)(e0 + wid * 32 + (lane >> 2)) * DP + srcsw;
  const f16* pB = WT + (size_t)(wid * 80 + (lane >> 2)) * DP + srcsw;

  f32x16 acc[2][5];
#pragma unroll
  for (int me = 0; me < 2; ++me)
#pragma unroll
    for (int f = 0; f < 5; ++f)
#pragma unroll
      for (int r = 0; r < 16; ++r) acc[me][f][r] = 0.f;

#define STAGE2(S)                                                              \
  {                                                                            \
    _Pragma("unroll") for (int i = 0; i < 2; ++i) {                            \
      GLOAD_LDS16(pA + (size_t)(i * 16) * DP,                                  \
                  lds + 40960 + (S)*8192 + wid * 2048 + i * 1024);             \
    }                                                                          \
    pA += 32;                                                                  \
    _Pragma("unroll") for (int i = 0; i < 5; ++i) {                            \
      GLOAD_LDS16(pB + (size_t)(i * 16) * DP,                                  \
                  lds + (S)*20480 + wid * 5120 + i * 1024);                    \
    }                                                                          \
    pB += 32;                                                                  \
  }

  STAGE2(0);
  STAGE2(1);
  K2WAIT(7);
  K2BAR();
  for (int tt = 0; tt < STEPS - 2; ++tt) {
    COMPUTE(tt & 1);
    K2BAR();
    STAGE2(tt & 1);   // step tt+2 into freed buffer
    K2WAIT(7);        // drain step tt+1
    K2BAR();
  }
  COMPUTE(0);
  K2BAR();
  K2WAIT(0);
  COMPUTE(1);

#pragma unroll
  for (int me = 0; me < 2; ++me)
#pragma unroll
    for (int f = 0; f < 5; ++f) {
      int jg = wj * 160 + f * 32 + l31;
      int ebase = e0 + we * 64 + me * 32 + 4 * oct;
#pragma unroll
      for (int r = 0; r < 16; ++r) {
        int eg = ebase + (r & 3) + 8 * (r >> 2);
        att[(size_t)eg * DP + jg] = acc[me][f][r];
      }
    }
#undef STAGE2
#undef COMPUTE
}

// ---------------------------------------------------------------- k3 v5: softmax(att) weights EF0 + projection
__global__ __launch_bounds__(256) void k3_edge(const float* __restrict__ att,
                                               const f16* __restrict__ EF0,
                                               const float* __restrict__ edge_feats,
                                               const float* __restrict__ Wproj,
                                               const float* __restrict__ alphaP,
                                               const float* __restrict__ ecWatt,
                                               float* __restrict__ ef,
                                               float* __restrict__ scores) {
  __shared__ float efw[16][304];
  const int t = threadIdx.x, lane = t & 63, w = t >> 6;
  const int e0 = blockIdx.x * 16;
  // phase 1: feature softmax over att row, weight EF0
  for (int el = 0; el < 4; ++el) {
    int e = e0 + w * 4 + el;
    const size_t ro = (size_t)e * DP;
    float p[5];
    float mx = -1e30f;
#pragma unroll
    for (int u = 0; u < 5; ++u) {
      int d = u * 64 + lane;
      p[u] = (d < ND) ? att[ro + d] : -1e30f;
      mx = fmaxf(mx, p[u]);
    }
    for (int o = 32; o; o >>= 1) mx = fmaxf(mx, __shfl_xor(mx, o));
    float s = 0.f;
#pragma unroll
    for (int u = 0; u < 5; ++u) {
      int d = u * 64 + lane;
      float pe = (d < ND) ? expf(p[u] - mx) : 0.f;
      p[u] = pe;
      s += pe;
    }
    for (int o = 32; o; o >>= 1) s += __shfl_xor(s, o);
    float inv = 1.f / s;
#pragma unroll
    for (int u = 0; u < 5; ++u) {
      int d = u * 64 + lane;
      if (d < 304)
        efw[w * 4 + el][d] = (d < ND) ? (float)EF0[ro + d] * p[u] * inv : 0.f;
    }
  }
  __syncthreads();
  // phase 2: register-blocked (ef0*attn) @ W_proj + residual + scores
  const int jl = lane & 15, kc = lane >> 4;
  const float alpha = alphaP[0];
  float acc[4][19];
#pragma unroll
  for (int ei = 0; ei < 4; ++ei)
#pragma unroll
    for (int jj = 0; jj < 19; ++jj) acc[ei][jj] = 0.f;
  const int d0 = kc * 75;
  const float* efw0 = &efw[w * 4 + 0][0];
  const float* efw1 = &efw[w * 4 + 1][0];
  const float* efw2 = &efw[w * 4 + 2][0];
  const float* efw3 = &efw[w * 4 + 3][0];
  for (int dd = 0; dd < 75; ++dd) {
    int d = d0 + dd;
    const float* wr = Wproj + (size_t)d * ND + jl;
    float w0 = efw0[d], w1 = efw1[d], w2 = efw2[d], w3 = efw3[d];
#pragma unroll
    for (int jj = 0; jj < 19; ++jj) {
      int j = jl + jj * 16;
      float wv = (j < ND) ? wr[jj * 16] : 0.f;
      acc[0][jj] += w0 * wv;
      acc[1][jj] += w1 * wv;
      acc[2][jj] += w2 * wv;
      acc[3][jj] += w3 * wv;
    }
  }
#pragma unroll
  for (int ei = 0; ei < 4; ++ei)
#pragma unroll
    for (int jj = 0; jj < 19; ++jj) {
      acc[ei][jj] += __shfl_xor(acc[ei][jj], 16);
      acc[ei][jj] += __shfl_xor(acc[ei][jj], 32);
    }
  float scp[4] = {0.f, 0.f, 0.f, 0.f};
#pragma unroll
  for (int ei = 0; ei < 4; ++ei) {
    int e = e0 + w * 4 + ei;
#pragma unroll
    for (int jj = 0; jj < 19; ++jj) {
      int j = jl + jj * 16;
      float v = 0.f;
      if (j < ND) {
        v = alpha * edge_feats[(size_t)e * ND + j] + (1.f - alpha) * acc[ei][jj];
        scp[ei] += v * ecWatt[j];
      }
      if (kc == 0) ef[(size_t)e * 304 + j] = v;
    }
  }
#pragma unroll
  for (int ei = 0; ei < 4; ++ei)
    for (int o = 8; o; o >>= 1) scp[ei] += __shfl_xor(scp[ei], o);
  if (lane == 0) {
#pragma unroll
    for (int ei = 0; ei < 4; ++ei) scores[e0 + w * 4 + ei] = scp[ei];
  }
}

// ---------------------------------------------------------------- k4a: softmax over 4096 edge scores
__global__ __launch_bounds__(1024) void k4a_softmax(const float* __restrict__ scores,
                                                    float* __restrict__ w) {
  __shared__ float red[16];
  __shared__ float red2[16];
  const int t = threadIdx.x, lane = t & 63, wv = t >> 6;
  float v[4];
  float mx = -1e30f;
#pragma unroll
  for (int u = 0; u < 4; ++u) {
    v[u] = scores[t + u * 1024];
    mx = fmaxf(mx, v[u]);
  }
  for (int o = 32; o; o >>= 1) mx = fmaxf(mx, __shfl_xor(mx, o));
  if (lane == 0) red[wv] = mx;
  __syncthreads();
  float m2 = red[0];
  for (int i = 1; i < 16; ++i) m2 = fmaxf(m2, red[i]);
  float s = 0.f;
#pragma unroll
  for (int u = 0; u < 4; ++u) {
    v[u] = expf(v[u] - m2);
    s += v[u];
  }
  for (int o = 32; o; o >>= 1) s += __shfl_xor(s, o);
  if (lane == 0) red2[wv] = s;
  __syncthreads();
  float S = 0.f;
  for (int i = 0; i < 16; ++i) S += red2[i];
  float inv = 1.f / S;
#pragma unroll
  for (int u = 0; u < 4; ++u) w[t + u * 1024] = v[u] * inv;
}

// ---------------------------------------------------------------- k4b: partial weighted pooling (64 edges/block)
__global__ __launch_bounds__(256) void k4b_pool(const float* __restrict__ ef,
                                                const float* __restrict__ w,
                                                float* __restrict__ partial) {
  const int b = blockIdx.x, t = threadIdx.x;
  const int e0 = b * 64;
  for (int j = t; j < 304; j += 256) {
    float acc = 0.f;
    for (int e = 0; e < 64; ++e) acc += w[e0 + e] * ef[(size_t)(e0 + e) * 304 + j];
    partial[b * 304 + j] = acc;
  }
}

// ---------------------------------------------------------------- k4c: final reduce + two matvecs -> 3 logits
__global__ __launch_bounds__(256) void k4c_final(const float* __restrict__ partial,
                                                 const float* __restrict__ ecWp,
                                                 const float* __restrict__ ecb,
                                                 const float* __restrict__ fcW,
                                                 const float* __restrict__ fcb,
                                                 float* __restrict__ out) {
  __shared__ float pooled[304];
  __shared__ float o[304];
  const int t = threadIdx.x;
  for (int j = t; j < 304; j += 256) {
    float acc = 0.f;
    for (int b = 0; b < 64; ++b) acc += partial[b * 304 + j];
    pooled[j] = acc;
  }
  __syncthreads();
  for (int j2 = t; j2 < ND; j2 += 256) {
    float acc = ecb[j2];
    for (int j = 0; j < ND; ++j) acc += pooled[j] * ecWp[j * ND + j2];
    o[j2] = acc;
  }
  __syncthreads();
  if (t < 3) {
    float acc = fcb[t];
    for (int j2 = 0; j2 < ND; ++j2) acc += o[j2] * fcW[j2 * 3 + t];
    out[t] = acc;
  }
}

// ----------------------------------------------------------------
extern "C" void kernel_launch(void* const* d_in, const int* in_sizes, int n_in,
                              void* d_out, int out_size, void* d_ws, size_t ws_size,
                              hipStream_t stream) {
  const float* X = (const float*)d_in[0];
  const float* EFEATS = (const float*)d_in[1];
  const float* INC = (const float*)d_in[2];
  const float* WATT = (const float*)d_in[3];
  const float* WPROJ = (const float*)d_in[4];
  const float* ALPHA = (const float*)d_in[5];
  const float* ECATT = (const float*)d_in[6];
  const float* ECWP = (const float*)d_in[7];
  const float* ECB = (const float*)d_in[8];
  const float* FCW = (const float*)d_in[9];
  const float* FCB = (const float*)d_in[10];

  char* ws = (char*)d_ws;
  f16* XT = (f16*)(ws);                    // [0, 10485760)
  f16* Zp = (f16*)(ws + 10485760);         // 16 x 2621440 B -> [10485760, 52428800)
  f16* WT = (f16*)(ws + 52428800);         // [52428800, 52633600)
  f16* EF0 = (f16*)(ws + 52633600);        // [52633600, 55255040)
  float* att = (float*)(ws + 55255040);    // [55255040, 60497920)
  float* ef = (float*)(ws + 60497920);     // [60497920, 65478656)
  float* sc = (float*)(ws + 65478656);     // 4096*4
  float* wv = (float*)(ws + 65495040);     // 4096*4
  float* pp = (float*)(ws + 65511424);     // 64*304*4

  hipLaunchKernelGGL(k0_wt, dim3(400), dim3(256), 0, stream, WATT, WT);
  hipLaunchKernelGGL(k1a_xprep, dim3(256), dim3(256), 0, stream, X, XT);
  hipLaunchKernelGGL(k2_bigmm, dim3(512), dim3(256), 0, stream, INC, XT, Zp);
  hipLaunchKernelGGL(k2s_sum, dim3(1280), dim3(256), 0, stream, Zp, EF0);
  hipLaunchKernelGGL(k2b_att, dim3(32), dim3(256), 0, stream, EF0, WT, att);
  hipLaunchKernelGGL(k3_edge, dim3(256), dim3(256), 0, stream, att, EF0, EFEATS,
                     WPROJ, ALPHA, ECATT, ef, sc);
  hipLaunchKernelGGL(k4a_softmax, dim3(1), dim3(1024), 0, stream, sc, wv);
  hipLaunchKernelGGL(k4b_pool, dim3(64), dim3(256), 0, stream, ef, wv, pp);
  hipLaunchKernelGGL(k4c_final, dim3(1), dim3(256), 0, stream, pp, ECWP, ECB, FCW,
                     FCB, (float*)d_out);
}

// Round 10
// 245.088 us; speedup vs baseline: 1.9305x; 1.0287x over previous
//
#include <hip/hip_runtime.h>
#include <math.h>

typedef _Float16 f16;
typedef _Float16 f16x8 __attribute__((ext_vector_type(8)));
typedef _Float16 f16x4 __attribute__((ext_vector_type(4)));
typedef __fp16 fp16x2 __attribute__((ext_vector_type(2)));
typedef float f32x4 __attribute__((ext_vector_type(4)));
typedef float f32x16 __attribute__((ext_vector_type(16)));

#define NM 16384    // nodes (K of big GEMM)
#define NE 4096     // hyperedges
#define ND 300      // feature dim
#define DP 320      // padded feature dim
#define PS 1310720  // per-partial f16 elements (4096*320)

__device__ __forceinline__ int swz(int r) { return (r ^ (r >> 2)) & 3; }

#define GLOAD_LDS16(gsrc, ldst)                                              \
  __builtin_amdgcn_global_load_lds(                                          \
      (__attribute__((address_space(1))) void*)(gsrc),                       \
      (__attribute__((address_space(3))) void*)(ldst), 16, 0, 0)

// ---------------------------------------------------------------- k01: X -> XT (f16, padded) + W_att^T -> f16
__global__ __launch_bounds__(256) void k01_prep(const float* __restrict__ X,
                                                const float* __restrict__ Watt,
                                                f16* __restrict__ XT,
                                                f16* __restrict__ WT) {
  __shared__ f16 tile[64][324];
  const int bx = blockIdx.x;
  if (bx < 256) {
    int m0 = bx * 64;
    for (int idx = threadIdx.x; idx < 64 * 80; idx += 256) {
      int m = idx / 80, q = idx % 80;
      int d = q * 4;
      float4 v = make_float4(0.f, 0.f, 0.f, 0.f);
      if (d < ND) v = *(const float4*)(X + (size_t)(m0 + m) * ND + d);
      tile[m][d] = (f16)v.x; tile[m][d + 1] = (f16)v.y;
      tile[m][d + 2] = (f16)v.z; tile[m][d + 3] = (f16)v.w;
    }
    __syncthreads();
    for (int idx = threadIdx.x; idx < DP * 8; idx += 256) {
      int d = idx >> 3, part = idx & 7;
      f16x8 hv;
#pragma unroll
      for (int i = 0; i < 8; ++i) hv[i] = tile[part * 8 + i][d];
      *(f16x8*)(XT + (size_t)d * NM + m0 + part * 8) = hv;
    }
  } else {
    int idx = (bx - 256) * 256 + threadIdx.x;
    if (idx < DP * DP) {
      int j = idx / DP, d = idx % DP;
      float v = (j < ND && d < ND) ? Watt[d * ND + j] : 0.f;
      WT[(size_t)j * DP + d] = (f16)v;
    }
  }
}

// ---------------------------------------------------------------- k2 v9: EF0 = inc^T @ X, 32x32x16 MFMA
// block 128e x 320j x BK32, 4 waves (2e x 2j), wave 64e x 160j (Ma=2,Nb=5).
// grid 512 = 32 eb x 16 kb, xcd = kb&7. LDS 56 KB ring-2 -> 2 blocks/CU.
// v9: double-buffered A registers -> issue LOADA/DMAB BEFORE the WRITEA stall.
// LDS: Bbuf[2] @ 0/20480 (320 rows x 64B); Abuf[2] @ 40960/49152 (128 rows x 64B)
#define K2WAIT(N) asm volatile("s_waitcnt vmcnt(" #N ") lgkmcnt(0)" ::: "memory")
#define K2BAR()                                        \
  do {                                                 \
    asm volatile("" ::: "memory");                     \
    __builtin_amdgcn_s_barrier();                      \
    asm volatile("" ::: "memory");                     \
  } while (0)

__global__ __launch_bounds__(256, 2) void k2_bigmm(const float* __restrict__ inc,
                                                   const f16* __restrict__ XT,
                                                   f16* __restrict__ Zp) {
  __shared__ __align__(16) char lds[57344];
  const int t = threadIdx.x, lane = t & 63, wid = t >> 6;
  const int bx = blockIdx.x;
  const int kb = (bx & 7) | (((bx >> 3) & 1) << 3);
  const int eb = bx >> 4;
  const int e0 = eb * 128;
  const size_t kbase = (size_t)kb * 1024;
  f16* __restrict__ Zout = Zp + (size_t)kb * PS;

  const int we = wid >> 1, wj = wid & 1;
  const int l31 = lane & 31, oct = lane >> 5;
  int sl[2];
#pragma unroll
  for (int kk = 0; kk < 2; ++kk)
    sl[kk] = (((kk * 2 + oct) ^ ((l31 >> 1) & 3)) & 3) << 4;
  const int arow = (we * 64 + l31) * 64;
  const int brow = (wj * 160 + l31) * 64;
  const int ep = t & 63, kq = t >> 6;
  const int sA = (kq ^ ((ep >> 1) & 3)) & 3;
  const int wa0 = 40960 + ep * 64 + sA * 16;
  const int wa1 = 40960 + (ep + 64) * 64 + sA * 16;
  const float* pA = inc + (kbase + kq * 8) * NE + e0 + ep;
  const int br = wid * 80 + (lane >> 2);
  const f16* pB = XT + (size_t)br * NM + kbase + 8 * ((lane & 3) ^ ((lane >> 3) & 3));

  float rAx0[8], rAy0[8], rAx1[8], rAy1[8];
  f32x16 acc[2][5];
#pragma unroll
  for (int me = 0; me < 2; ++me)
#pragma unroll
    for (int f = 0; f < 5; ++f)
#pragma unroll
      for (int r = 0; r < 16; ++r) acc[me][f][r] = 0.f;

#define LOADA(RX, RY)                                                          \
  {                                                                            \
    _Pragma("unroll") for (int i = 0; i < 8; ++i) {                            \
      RX[i] = pA[(size_t)i * NE];                                              \
      RY[i] = pA[(size_t)i * NE + 64];                                         \
    }                                                                          \
    pA += (size_t)32 * NE;                                                     \
  }
#define DMAB(S)                                                                \
  {                                                                            \
    _Pragma("unroll") for (int i = 0; i < 5; ++i) {                            \
      GLOAD_LDS16(pB + (size_t)(i * 16) * NM,                                  \
                  lds + (S)*20480 + wid * 5120 + i * 1024);                    \
    }                                                                          \
    pB += 32;                                                                  \
  }
#define WRITEA(RX, RY, S)                                                      \
  {                                                                            \
    union { fp16x2 h; uint32_t u; } ux_[4], uy_[4];                            \
    _Pragma("unroll") for (int z = 0; z < 4; ++z) {                            \
      ux_[z].h = __builtin_amdgcn_cvt_pkrtz(RX[2 * z], RX[2 * z + 1]);         \
      uy_[z].h = __builtin_amdgcn_cvt_pkrtz(RY[2 * z], RY[2 * z + 1]);         \
    }                                                                          \
    *(uint4*)(lds + wa0 + (S)*8192) =                                          \
        make_uint4(ux_[0].u, ux_[1].u, ux_[2].u, ux_[3].u);                    \
    *(uint4*)(lds + wa1 + (S)*8192) =                                          \
        make_uint4(uy_[0].u, uy_[1].u, uy_[2].u, uy_[3].u);                    \
  }
#define COMPUTE(S)                                                             \
  {                                                                            \
    __builtin_amdgcn_s_setprio(1);                                             \
    _Pragma("unroll") for (int kk = 0; kk < 2; ++kk) {                         \
      f16x8 a0_ = *(const f16x8*)(lds + 40960 + (S)*8192 + arow + sl[kk]);     \
      f16x8 a1_ = *(const f16x8*)(lds + 40960 + (S)*8192 + arow + 2048 + sl[kk]); \
      _Pragma("unroll") for (int f = 0; f < 5; ++f) {                          \
        f16x8 b_ = *(const f16x8*)(lds + (S)*20480 + brow + f * 2048 + sl[kk]); \
        acc[0][f] = __builtin_amdgcn_mfma_f32_32x32x16_f16(a0_, b_, acc[0][f], 0, 0, 0); \
        acc[1][f] = __builtin_amdgcn_mfma_f32_32x32x16_f16(a1_, b_, acc[1][f], 0, 0, 0); \
      }                                                                        \
    }                                                                          \
    __builtin_amdgcn_s_setprio(0);                                             \
  }

  // prologue: A(0)->s0, B(0); write A(0); A(1)->s0, B(1)
  LOADA(rAx0, rAy0);       // A(0)
  DMAB(0);                 // B(0)
  WRITEA(rAx0, rAy0, 0);   // implicit wait A(0)
  LOADA(rAx0, rAy0);       // A(1)
  DMAB(1);                 // B(1); outstanding 26
  K2WAIT(21);              // drain B(0)
  K2BAR();

  // main loop: iterations 0..29 (15 unrolled pairs)
  for (int it = 0; it < 15; ++it) {
    // even tt: s0 = A(tt+1)
    COMPUTE(0);
    K2BAR();
    LOADA(rAx1, rAy1);       // A(tt+2) -> other set (issued before the stall)
    DMAB(0);                 // B(tt+2)
    WRITEA(rAx0, rAy0, 1);   // A(tt+1); implicit wait vmcnt(26)
    K2WAIT(21);              // drain B(tt+1)
    K2BAR();
    // odd tt+1: s1 = A(tt+2)
    COMPUTE(1);
    K2BAR();
    LOADA(rAx0, rAy0);       // A(tt+3)
    DMAB(1);                 // B(tt+3)
    WRITEA(rAx1, rAy1, 0);   // A(tt+2)
    K2WAIT(21);              // drain B(tt+2)
    K2BAR();
  }
  // tt=30: s0 = A(31)
  COMPUTE(0);
  K2BAR();
  WRITEA(rAx0, rAy0, 1);   // A(31); implicit wait vmcnt(5)
  K2WAIT(0);               // drain B(31)
  K2BAR();
  // tt=31
  COMPUTE(1);

  // epilogue: f16 partial store (C/D: col=lane&31 -> j, row=(r&3)+8*(r>>2)+4*oct -> e)
#pragma unroll
  for (int me = 0; me < 2; ++me)
#pragma unroll
    for (int f = 0; f < 5; ++f) {
      int jg = wj * 160 + f * 32 + l31;
      int ebase = e0 + we * 64 + me * 32 + 4 * oct;
#pragma unroll
      for (int r = 0; r < 16; ++r) {
        int eg = ebase + (r & 3) + 8 * (r >> 2);
        Zout[(size_t)eg * DP + jg] = (f16)acc[me][f][r];
      }
    }
#undef LOADA
#undef DMAB
#undef WRITEA
}

// ---------------------------------------------------------------- k2s: sum 16 f16 partials -> EF0 (f16)
__global__ __launch_bounds__(256) void k2s_sum(const f16* __restrict__ Zp,
                                               f16* __restrict__ EF0) {
  const int idx = (blockIdx.x * 256 + threadIdx.x) * 4;
  float s0 = 0.f, s1 = 0.f, s2 = 0.f, s3 = 0.f;
#pragma unroll
  for (int i = 0; i < 16; ++i) {
    f16x4 v = *(const f16x4*)(Zp + (size_t)i * PS + idx);
    s0 += (float)v[0]; s1 += (float)v[1]; s2 += (float)v[2]; s3 += (float)v[3];
  }
  f16x4 o;
  o[0] = (f16)s0; o[1] = (f16)s1; o[2] = (f16)s2; o[3] = (f16)s3;
  *(f16x4*)(EF0 + idx) = o;
}

// ---------------------------------------------------------------- k2b: att = EF0 @ W_att (f32 out), 32 blocks
__global__ __launch_bounds__(256, 1) void k2b_att(const f16* __restrict__ EF0,
                                                  const f16* __restrict__ WT,
                                                  float* __restrict__ att) {
  constexpr int STEPS = 10;
  __shared__ __align__(16) char lds[57344];
  const int t = threadIdx.x, lane = t & 63, wid = t >> 6;
  const int e0 = blockIdx.x * 128;
  const int we = wid >> 1, wj = wid & 1;
  const int l31 = lane & 31, oct = lane >> 5;
  int sl[2];
#pragma unroll
  for (int kk = 0; kk < 2; ++kk)
    sl[kk] = (((kk * 2 + oct) ^ ((l31 >> 1) & 3)) & 3) << 4;
  const int arow = (we * 64 + l31) * 64;
  const int brow = (wj * 160 + l31) * 64;
  const int srcsw = 8 * ((lane & 3) ^ ((lane >> 3) & 3));
  const f16* pA = EF0 + (size_t)(e0 + wid * 32 + (lane >> 2)) * DP + srcsw;
  const f16* pB = WT + (size_t)(wid * 80 + (lane >> 2)) * DP + srcsw;

  f32x16 acc[2][5];
#pragma unroll
  for (int me = 0; me < 2; ++me)
#pragma unroll
    for (int f = 0; f < 5; ++f)
#pragma unroll
      for (int r = 0; r < 16; ++r) acc[me][f][r] = 0.f;

#define STAGE2(S)                                                              \
  {                                                                            \
    _Pragma("unroll") for (int i = 0; i < 2; ++i) {                            \
      GLOAD_LDS16(pA + (size_t)(i * 16) * DP,                                  \
                  lds + 40960 + (S)*8192 + wid * 2048 + i * 1024);             \
    }                                                                          \
    pA += 32;                                                                  \
    _Pragma("unroll") for (int i = 0; i < 5; ++i) {                            \
      GLOAD_LDS16(pB + (size_t)(i * 16) * DP,                                  \
                  lds + (S)*20480 + wid * 5120 + i * 1024);                    \
    }                                                                          \
    pB += 32;                                                                  \
  }

  STAGE2(0);
  STAGE2(1);
  K2WAIT(7);
  K2BAR();
  for (int tt = 0; tt < STEPS - 2; ++tt) {
    COMPUTE(tt & 1);
    K2BAR();
    STAGE2(tt & 1);
    K2WAIT(7);
    K2BAR();
  }
  COMPUTE(0);
  K2BAR();
  K2WAIT(0);
  COMPUTE(1);

#pragma unroll
  for (int me = 0; me < 2; ++me)
#pragma unroll
    for (int f = 0; f < 5; ++f) {
      int jg = wj * 160 + f * 32 + l31;
      int ebase = e0 + we * 64 + me * 32 + 4 * oct;
#pragma unroll
      for (int r = 0; r < 16; ++r) {
        int eg = ebase + (r & 3) + 8 * (r >> 2);
        att[(size_t)eg * DP + jg] = acc[me][f][r];
      }
    }
#undef STAGE2
#undef COMPUTE
}

// ---------------------------------------------------------------- k3: softmax(att) weights EF0 + projection
__global__ __launch_bounds__(256) void k3_edge(const float* __restrict__ att,
                                               const f16* __restrict__ EF0,
                                               const float* __restrict__ edge_feats,
                                               const float* __restrict__ Wproj,
                                               const float* __restrict__ alphaP,
                                               const float* __restrict__ ecWatt,
                                               float* __restrict__ ef,
                                               float* __restrict__ scores) {
  __shared__ float efw[16][304];
  const int t = threadIdx.x, lane = t & 63, w = t >> 6;
  const int e0 = blockIdx.x * 16;
  for (int el = 0; el < 4; ++el) {
    int e = e0 + w * 4 + el;
    const size_t ro = (size_t)e * DP;
    float p[5];
    float mx = -1e30f;
#pragma unroll
    for (int u = 0; u < 5; ++u) {
      int d = u * 64 + lane;
      p[u] = (d < ND) ? att[ro + d] : -1e30f;
      mx = fmaxf(mx, p[u]);
    }
    for (int o = 32; o; o >>= 1) mx = fmaxf(mx, __shfl_xor(mx, o));
    float s = 0.f;
#pragma unroll
    for (int u = 0; u < 5; ++u) {
      int d = u * 64 + lane;
      float pe = (d < ND) ? expf(p[u] - mx) : 0.f;
      p[u] = pe;
      s += pe;
    }
    for (int o = 32; o; o >>= 1) s += __shfl_xor(s, o);
    float inv = 1.f / s;
#pragma unroll
    for (int u = 0; u < 5; ++u) {
      int d = u * 64 + lane;
      if (d < 304)
        efw[w * 4 + el][d] = (d < ND) ? (float)EF0[ro + d] * p[u] * inv : 0.f;
    }
  }
  __syncthreads();
  const int jl = lane & 15, kc = lane >> 4;
  const float alpha = alphaP[0];
  float acc[4][19];
#pragma unroll
  for (int ei = 0; ei < 4; ++ei)
#pragma unroll
    for (int jj = 0; jj < 19; ++jj) acc[ei][jj] = 0.f;
  const int d0 = kc * 75;
  const float* efw0 = &efw[w * 4 + 0][0];
  const float* efw1 = &efw[w * 4 + 1][0];
  const float* efw2 = &efw[w * 4 + 2][0];
  const float* efw3 = &efw[w * 4 + 3][0];
  for (int dd = 0; dd < 75; ++dd) {
    int d = d0 + dd;
    const float* wr = Wproj + (size_t)d * ND + jl;
    float w0 = efw0[d], w1 = efw1[d], w2 = efw2[d], w3 = efw3[d];
#pragma unroll
    for (int jj = 0; jj < 19; ++jj) {
      int j = jl + jj * 16;
      float wv = (j < ND) ? wr[jj * 16] : 0.f;
      acc[0][jj] += w0 * wv;
      acc[1][jj] += w1 * wv;
      acc[2][jj] += w2 * wv;
      acc[3][jj] += w3 * wv;
    }
  }
#pragma unroll
  for (int ei = 0; ei < 4; ++ei)
#pragma unroll
    for (int jj = 0; jj < 19; ++jj) {
      acc[ei][jj] += __shfl_xor(acc[ei][jj], 16);
      acc[ei][jj] += __shfl_xor(acc[ei][jj], 32);
    }
  float scp[4] = {0.f, 0.f, 0.f, 0.f};
#pragma unroll
  for (int ei = 0; ei < 4; ++ei) {
    int e = e0 + w * 4 + ei;
#pragma unroll
    for (int jj = 0; jj < 19; ++jj) {
      int j = jl + jj * 16;
      float v = 0.f;
      if (j < ND) {
        v = alpha * edge_feats[(size_t)e * ND + j] + (1.f - alpha) * acc[ei][jj];
        scp[ei] += v * ecWatt[j];
      }
      if (kc == 0) ef[(size_t)e * 304 + j] = v;
    }
  }
#pragma unroll
  for (int ei = 0; ei < 4; ++ei)
    for (int o = 8; o; o >>= 1) scp[ei] += __shfl_xor(scp[ei], o);
  if (lane == 0) {
#pragma unroll
    for (int ei = 0; ei < 4; ++ei) scores[e0 + w * 4 + ei] = scp[ei];
  }
}

// ---------------------------------------------------------------- k4ab: per-block softmax recompute + weighted pooling
__global__ __launch_bounds__(256) void k4ab_pool(const float* __restrict__ sc,
                                                 const float* __restrict__ ef,
                                                 float* __restrict__ pp) {
  __shared__ float redm[4];
  __shared__ float reds[4];
  __shared__ float wsh[64];
  const int t = threadIdx.x, lane = t & 63, w = t >> 6;
  float v[16];
  float mx = -1e30f;
#pragma unroll
  for (int u = 0; u < 16; ++u) {
    v[u] = sc[t + u * 256];
    mx = fmaxf(mx, v[u]);
  }
  for (int o = 32; o; o >>= 1) mx = fmaxf(mx, __shfl_xor(mx, o));
  if (lane == 0) redm[w] = mx;
  __syncthreads();
  float m2 = fmaxf(fmaxf(redm[0], redm[1]), fmaxf(redm[2], redm[3]));
  float s = 0.f;
#pragma unroll
  for (int u = 0; u < 16; ++u) s += expf(v[u] - m2);
  for (int o = 32; o; o >>= 1) s += __shfl_xor(s, o);
  if (lane == 0) reds[w] = s;
  __syncthreads();
  float inv = 1.f / (reds[0] + reds[1] + reds[2] + reds[3]);
  const int e0 = blockIdx.x * 64;
  if (t < 64) wsh[t] = expf(sc[e0 + t] - m2) * inv;
  __syncthreads();
  for (int j = t; j < 304; j += 256) {
    float acc = 0.f;
#pragma unroll 8
    for (int e = 0; e < 64; ++e) acc += wsh[e] * ef[(size_t)(e0 + e) * 304 + j];
    pp[blockIdx.x * 304 + j] = acc;
  }
}

// ---------------------------------------------------------------- k4c: final reduce + two matvecs -> 3 logits
__global__ __launch_bounds__(320) void k4c_final(const float* __restrict__ pp,
                                                 const float* __restrict__ ecWp,
                                                 const float* __restrict__ ecb,
                                                 const float* __restrict__ fcW,
                                                 const float* __restrict__ fcb,
                                                 float* __restrict__ out) {
  __shared__ float pooled[304];
  __shared__ float o[304];
  const int t = threadIdx.x;
  if (t < 304) {
    float acc = 0.f;
#pragma unroll 8
    for (int b = 0; b < 64; ++b) acc += pp[b * 304 + t];
    pooled[t] = acc;
  }
  __syncthreads();
  if (t < ND) {
    float acc = ecb[t];
#pragma unroll 4
    for (int j = 0; j < ND; ++j) acc += pooled[j] * ecWp[(size_t)j * ND + t];
    o[t] = acc;
  }
  __syncthreads();
  if (t < 64) {
#pragma unroll
    for (int c = 0; c < 3; ++c) {
      float a = 0.f;
      for (int j2 = t; j2 < ND; j2 += 64) a += o[j2] * fcW[j2 * 3 + c];
      for (int off = 32; off; off >>= 1) a += __shfl_xor(a, off);
      if (t == 0) out[c] = a + fcb[c];
    }
  }
}

// ----------------------------------------------------------------
extern "C" void kernel_launch(void* const* d_in, const int* in_sizes, int n_in,
                              void* d_out, int out_size, void* d_ws, size_t ws_size,
                              hipStream_t stream) {
  const float* X = (const float*)d_in[0];
  const float* EFEATS = (const float*)d_in[1];
  const float* INC = (const float*)d_in[2];
  const float* WATT = (const float*)d_in[3];
  const float* WPROJ = (const float*)d_in[4];
  const float* ALPHA = (const float*)d_in[5];
  const float* ECATT = (const float*)d_in[6];
  const float* ECWP = (const float*)d_in[7];
  const float* ECB = (const float*)d_in[8];
  const float* FCW = (const float*)d_in[9];
  const float* FCB = (const float*)d_in[10];

  char* ws = (char*)d_ws;
  f16* XT = (f16*)(ws);                    // [0, 10485760)
  f16* Zp = (f16*)(ws + 10485760);         // 16 x 2621440 B -> [10485760, 52428800)
  f16* WT = (f16*)(ws + 52428800);         // [52428800, 52633600)
  f16* EF0 = (f16*)(ws + 52633600);        // [52633600, 55255040)
  float* att = (float*)(ws + 55255040);    // [55255040, 60497920)
  float* ef = (float*)(ws + 60497920);     // [60497920, 65478656)
  float* sc = (float*)(ws + 65478656);     // 4096*4
  float* pp = (float*)(ws + 65495040);     // 64*304*4

  hipLaunchKernelGGL(k01_prep, dim3(656), dim3(256), 0, stream, X, WATT, XT, WT);
  hipLaunchKernelGGL(k2_bigmm, dim3(512), dim3(256), 0, stream, INC, XT, Zp);
  hipLaunchKernelGGL(k2s_sum, dim3(1280), dim3(256), 0, stream, Zp, EF0);
  hipLaunchKernelGGL(k2b_att, dim3(32), dim3(256), 0, stream, EF0, WT, att);
  hipLaunchKernelGGL(k3_edge, dim3(256), dim3(256), 0, stream, att, EF0, EFEATS,
                     WPROJ, ALPHA, ECATT, ef, sc);
  hipLaunchKernelGGL(k4ab_pool, dim3(64), dim3(256), 0, stream, sc, ef, pp);
  hipLaunchKernelGGL(k4c_final, dim3(1), dim3(320), 0, stream, pp, ECWP, ECB, FCW,
                     FCB, (float*)d_out);
}

// Round 11
// 242.583 us; speedup vs baseline: 1.9505x; 1.0103x over previous
//
#include <hip/hip_runtime.h>
#include <math.h>

typedef _Float16 f16;
typedef _Float16 f16x8 __attribute__((ext_vector_type(8)));
typedef _Float16 f16x4 __attribute__((ext_vector_type(4)));
typedef __fp16 fp16x2 __attribute__((ext_vector_type(2)));
typedef float f32x4 __attribute__((ext_vector_type(4)));
typedef float f32x16 __attribute__((ext_vector_type(16)));

#define NM 16384    // nodes (K of big GEMM)
#define NE 4096     // hyperedges
#define ND 300      // feature dim
#define DP 320      // padded feature dim
#define PS 1310720  // per-partial f16 elements (4096*320)

#define GLOAD_LDS16(gsrc, ldst)                                              \
  __builtin_amdgcn_global_load_lds(                                          \
      (__attribute__((address_space(1))) void*)(gsrc),                       \
      (__attribute__((address_space(3))) void*)(ldst), 16, 0, 0)

#define K2WAIT(N) asm volatile("s_waitcnt vmcnt(" #N ") lgkmcnt(0)" ::: "memory")
#define K2BAR()                                        \
  do {                                                 \
    asm volatile("" ::: "memory");                     \
    __builtin_amdgcn_s_barrier();                      \
    asm volatile("" ::: "memory");                     \
  } while (0)
#define K2BARW()                                       \
  do {                                                 \
    asm volatile("s_waitcnt lgkmcnt(0)" ::: "memory"); \
    __builtin_amdgcn_s_barrier();                      \
    asm volatile("" ::: "memory");                     \
  } while (0)

// ---------------------------------------------------------------- k01: X -> XT (f16, padded) + W_att^T -> f16
__global__ __launch_bounds__(256) void k01_prep(const float* __restrict__ X,
                                                const float* __restrict__ Watt,
                                                f16* __restrict__ XT,
                                                f16* __restrict__ WT) {
  __shared__ f16 tile[64][324];
  const int bx = blockIdx.x;
  if (bx < 256) {
    int m0 = bx * 64;
    for (int idx = threadIdx.x; idx < 64 * 80; idx += 256) {
      int m = idx / 80, q = idx % 80;
      int d = q * 4;
      float4 v = make_float4(0.f, 0.f, 0.f, 0.f);
      if (d < ND) v = *(const float4*)(X + (size_t)(m0 + m) * ND + d);
      tile[m][d] = (f16)v.x; tile[m][d + 1] = (f16)v.y;
      tile[m][d + 2] = (f16)v.z; tile[m][d + 3] = (f16)v.w;
    }
    __syncthreads();
    for (int idx = threadIdx.x; idx < DP * 8; idx += 256) {
      int d = idx >> 3, part = idx & 7;
      f16x8 hv;
#pragma unroll
      for (int i = 0; i < 8; ++i) hv[i] = tile[part * 8 + i][d];
      *(f16x8*)(XT + (size_t)d * NM + m0 + part * 8) = hv;
    }
  } else {
    int idx = (bx - 256) * 256 + threadIdx.x;
    if (idx < DP * DP) {
      int j = idx / DP, d = idx % DP;
      float v = (j < ND && d < ND) ? Watt[d * ND + j] : 0.f;
      WT[(size_t)j * DP + d] = (f16)v;
    }
  }
}

// ---------------------------------------------------------------- k2 v10: EF0 = inc^T @ X, 32x32x16 MFMA
// block 128e x 320j x BK32, 4 waves (2e x 2j), wave 64e x 160j (Ma=2,Nb=5).
// grid 512 = 32 eb x 16 kb, xcd = kb&7. B-ring-3 + A-ring-2, single implicit
// vmcnt per step (WRITEA's A(t+1) wait proves B(t+1) resident, in-order).
// LDS: B @ 0/20480/40960 (320 rows x 64B); A @ 61440/69632 (128 rows x 64B)
__global__ __launch_bounds__(256, 2) void k2_bigmm(const float* __restrict__ inc,
                                                   const f16* __restrict__ XT,
                                                   f16* __restrict__ Zp) {
  __shared__ __align__(16) char lds[77824];
  const int t = threadIdx.x, lane = t & 63, wid = t >> 6;
  const int bx = blockIdx.x;
  const int kb = (bx & 7) | (((bx >> 3) & 1) << 3);
  const int eb = bx >> 4;
  const int e0 = eb * 128;
  const size_t kbase = (size_t)kb * 1024;
  f16* __restrict__ Zout = Zp + (size_t)kb * PS;

  const int we = wid >> 1, wj = wid & 1;
  const int l31 = lane & 31, oct = lane >> 5;
  int sl[2];
#pragma unroll
  for (int kk = 0; kk < 2; ++kk)
    sl[kk] = (((kk * 2 + oct) ^ ((l31 >> 1) & 3)) & 3) << 4;
  const int arow = (we * 64 + l31) * 64;
  const int brow = (wj * 160 + l31) * 64;
  // A staging: lane ep -> e-pair {2ep, 2ep+1}; kq = k-chunk of 8
  const int ep = t & 63, kq = t >> 6;
  const int sA = (kq ^ (ep & 3)) & 3;
  const int wa0 = 61440 + ep * 128 + sA * 16;  // row 2ep; row 2ep+1 at +64
  const float* pA = inc + (kbase + kq * 8) * NE + e0 + 2 * ep;
  const int br = wid * 80 + (lane >> 2);
  const f16* pB = XT + (size_t)br * NM + kbase + 8 * ((lane & 3) ^ ((lane >> 3) & 3));

  float2 rA0[8], rA1[8];
  f32x16 acc[2][5];
#pragma unroll
  for (int me = 0; me < 2; ++me)
#pragma unroll
    for (int f = 0; f < 5; ++f)
#pragma unroll
      for (int r = 0; r < 16; ++r) acc[me][f][r] = 0.f;

#define LOADA(R)                                                               \
  {                                                                            \
    _Pragma("unroll") for (int i = 0; i < 8; ++i)                              \
        R[i] = *(const float2*)(pA + (size_t)i * NE);                          \
    pA += (size_t)32 * NE;                                                     \
  }
#define DMAB(S)                                                                \
  {                                                                            \
    _Pragma("unroll") for (int i = 0; i < 5; ++i) {                            \
      GLOAD_LDS16(pB + (size_t)(i * 16) * NM,                                  \
                  lds + (S)*20480 + wid * 5120 + i * 1024);                    \
    }                                                                          \
    pB += 32;                                                                  \
  }
#define WRITEA(R, S)                                                           \
  {                                                                            \
    union { fp16x2 h; uint32_t u; } ux_[4], uy_[4];                            \
    _Pragma("unroll") for (int z = 0; z < 4; ++z) {                            \
      ux_[z].h = __builtin_amdgcn_cvt_pkrtz(R[2 * z].x, R[2 * z + 1].x);       \
      uy_[z].h = __builtin_amdgcn_cvt_pkrtz(R[2 * z].y, R[2 * z + 1].y);       \
    }                                                                          \
    *(uint4*)(lds + wa0 + (S)*8192) =                                          \
        make_uint4(ux_[0].u, ux_[1].u, ux_[2].u, ux_[3].u);                    \
    *(uint4*)(lds + wa0 + 64 + (S)*8192) =                                     \
        make_uint4(uy_[0].u, uy_[1].u, uy_[2].u, uy_[3].u);                    \
  }
#define COMPUTE(BS, AS)                                                        \
  {                                                                            \
    __builtin_amdgcn_s_setprio(1);                                             \
    _Pragma("unroll") for (int kk = 0; kk < 2; ++kk) {                         \
      f16x8 a0_ = *(const f16x8*)(lds + 61440 + (AS)*8192 + arow + sl[kk]);    \
      f16x8 a1_ = *(const f16x8*)(lds + 61440 + (AS)*8192 + arow + 2048 + sl[kk]); \
      _Pragma("unroll") for (int f = 0; f < 5; ++f) {                          \
        f16x8 b_ = *(const f16x8*)(lds + (BS)*20480 + brow + f * 2048 + sl[kk]); \
        acc[0][f] = __builtin_amdgcn_mfma_f32_32x32x16_f16(a0_, b_, acc[0][f], 0, 0, 0); \
        acc[1][f] = __builtin_amdgcn_mfma_f32_32x32x16_f16(a1_, b_, acc[1][f], 0, 0, 0); \
      }                                                                        \
    }                                                                          \
    __builtin_amdgcn_s_setprio(0);                                             \
  }
// BODY(tt): stage B(tt+2), load A(tt+2), write A(tt+1); barrier; compute tt.
#define BODY(BSTG, BCMP, AW, AC, RL, RW)                                       \
  DMAB(BSTG);                                                                  \
  LOADA(RL);                                                                   \
  WRITEA(RW, AW); /* implicit vmcnt drains A(tt+1) => B(tt),B(tt+1) resident */\
  K2BARW();                                                                    \
  COMPUTE(BCMP, AC);                                                           \
  K2BAR();

  // prologue
  LOADA(rA0);        // A(0)
  DMAB(0);           // B(0)
  WRITEA(rA0, 0);    // A(0) -> Abuf0 (implicit wait A(0))
  LOADA(rA1);        // A(1)
  DMAB(1);           // B(1)
  BODY(2, 0, 1, 0, rA0, rA1);   // tt=0

  for (int it = 0; it < 4; ++it) {  // tt = 1..24
    BODY(0, 1, 0, 1, rA1, rA0);     // tt%6=1
    BODY(1, 2, 1, 0, rA0, rA1);     // 2
    BODY(2, 0, 0, 1, rA1, rA0);     // 3
    BODY(0, 1, 1, 0, rA0, rA1);     // 4
    BODY(1, 2, 0, 1, rA1, rA0);     // 5
    BODY(2, 0, 1, 0, rA0, rA1);     // 0
  }
  BODY(0, 1, 0, 1, rA1, rA0);  // tt=25
  BODY(1, 2, 1, 0, rA0, rA1);  // 26
  BODY(2, 0, 0, 1, rA1, rA0);  // 27
  BODY(0, 1, 1, 0, rA0, rA1);  // 28
  BODY(1, 2, 0, 1, rA1, rA0);  // 29
  // tail tt=30: write A(31), drain everything
  WRITEA(rA1, 1);
  K2WAIT(0);
  K2BAR();
  COMPUTE(0, 0);   // step 30: B 30%3=0, A 30&1=0
  K2BAR();
  COMPUTE(1, 1);   // step 31: B 31%3=1, A 31&1=1

  // epilogue: f16 partial store (C/D: col=lane&31 -> j, row=(r&3)+8*(r>>2)+4*oct -> e)
#pragma unroll
  for (int me = 0; me < 2; ++me)
#pragma unroll
    for (int f = 0; f < 5; ++f) {
      int jg = wj * 160 + f * 32 + l31;
      int ebase = e0 + we * 64 + me * 32 + 4 * oct;
#pragma unroll
      for (int r = 0; r < 16; ++r) {
        int eg = ebase + (r & 3) + 8 * (r >> 2);
        Zout[(size_t)eg * DP + jg] = (f16)acc[me][f][r];
      }
    }
#undef LOADA
#undef DMAB
#undef WRITEA
#undef COMPUTE
#undef BODY
}

// ---------------------------------------------------------------- k2bs: fused partial-sum (-> EF0) + att = EF0 @ W_att
// 64 blocks x 64 e-rows. Phase A: sum 16 f16 partials for own slab -> EF0.
// Phase B: 64e x 320j MFMA GEMM, K=320 (10 steps), both operands staged.
// LDS: Bbuf[2] @ 0/20480 (320 rows x 64B); Abuf[2] @ 40960/45056 (64 rows x 64B)
__global__ __launch_bounds__(256, 1) void k2bs_att(const f16* __restrict__ Zp,
                                                   const f16* __restrict__ WT,
                                                   f16* __restrict__ EF0,
                                                   float* __restrict__ att) {
  __shared__ __align__(16) char lds[49152];
  const int t = threadIdx.x, lane = t & 63, wid = t >> 6;
  const int e0 = blockIdx.x * 64;
  // ---- phase A: EF0[e0..e0+63][0..319] = sum_p Zp[p]
  {
    const size_t base = (size_t)e0 * DP;
    for (int i = t; i < 2560; i += 256) {  // 64*320/8 f16x8 groups
      size_t idx = base + (size_t)i * 8;
      float s[8];
#pragma unroll
      for (int z = 0; z < 8; ++z) s[z] = 0.f;
#pragma unroll
      for (int p = 0; p < 16; ++p) {
        f16x8 v = *(const f16x8*)(Zp + (size_t)p * PS + idx);
#pragma unroll
        for (int z = 0; z < 8; ++z) s[z] += (float)v[z];
      }
      f16x8 o;
#pragma unroll
      for (int z = 0; z < 8; ++z) o[z] = (f16)s[z];
      *(f16x8*)(EF0 + idx) = o;
    }
    asm volatile("s_waitcnt vmcnt(0)" ::: "memory");
    __syncthreads();
  }
  // ---- phase B: att slab = EF0 slab @ WT
  const int we = wid >> 1, wj = wid & 1;
  const int l31 = lane & 31, oct = lane >> 5;
  int sl[2];
#pragma unroll
  for (int kk = 0; kk < 2; ++kk)
    sl[kk] = (((kk * 2 + oct) ^ ((l31 >> 1) & 3)) & 3) << 4;
  const int arow = (we * 32 + l31) * 64;
  const int brow = (wj * 160 + l31) * 64;
  const int srcsw = 8 * ((lane & 3) ^ ((lane >> 3) & 3));
  const f16* pA = EF0 + (size_t)(e0 + wid * 16 + (lane >> 2)) * DP + srcsw;
  const f16* pB = WT + (size_t)(wid * 80 + (lane >> 2)) * DP + srcsw;

  f32x16 acc[5];
#pragma unroll
  for (int f = 0; f < 5; ++f)
#pragma unroll
    for (int r = 0; r < 16; ++r) acc[f][r] = 0.f;

#define STAGE2(S)                                                              \
  {                                                                            \
    GLOAD_LDS16(pA, lds + 40960 + (S)*4096 + wid * 1024);                      \
    pA += 32;                                                                  \
    _Pragma("unroll") for (int i = 0; i < 5; ++i) {                            \
      GLOAD_LDS16(pB + (size_t)(i * 16) * DP,                                  \
                  lds + (S)*20480 + wid * 5120 + i * 1024);                    \
    }                                                                          \
    pB += 32;                                                                  \
  }
#define COMPUTE2(S)                                                            \
  {                                                                            \
    _Pragma("unroll") for (int kk = 0; kk < 2; ++kk) {                         \
      f16x8 a_ = *(const f16x8*)(lds + 40960 + (S)*4096 + arow + sl[kk]);      \
      _Pragma("unroll") for (int f = 0; f < 5; ++f) {                          \
        f16x8 b_ = *(const f16x8*)(lds + (S)*20480 + brow + f * 2048 + sl[kk]); \
        acc[f] = __builtin_amdgcn_mfma_f32_32x32x16_f16(a_, b_, acc[f], 0, 0, 0); \
      }                                                                        \
    }                                                                          \
  }

  STAGE2(0);
  STAGE2(1);
  K2WAIT(6);
  K2BAR();
  for (int tt = 0; tt < 8; ++tt) {
    COMPUTE2(tt & 1);
    K2BAR();
    STAGE2(tt & 1);
    K2WAIT(6);
    K2BAR();
  }
  COMPUTE2(0);
  K2BAR();
  K2WAIT(0);
  COMPUTE2(1);

#pragma unroll
  for (int f = 0; f < 5; ++f) {
    int jg = wj * 160 + f * 32 + l31;
    int ebase = e0 + we * 32 + 4 * oct;
#pragma unroll
    for (int r = 0; r < 16; ++r) {
      int eg = ebase + (r & 3) + 8 * (r >> 2);
      att[(size_t)eg * DP + jg] = acc[f][r];
    }
  }
#undef STAGE2
#undef COMPUTE2
}

// ---------------------------------------------------------------- k3: softmax(att) weights EF0 + projection
__global__ __launch_bounds__(256) void k3_edge(const float* __restrict__ att,
                                               const f16* __restrict__ EF0,
                                               const float* __restrict__ edge_feats,
                                               const float* __restrict__ Wproj,
                                               const float* __restrict__ alphaP,
                                               const float* __restrict__ ecWatt,
                                               float* __restrict__ ef,
                                               float* __restrict__ scores) {
  __shared__ float efw[16][304];
  const int t = threadIdx.x, lane = t & 63, w = t >> 6;
  const int e0 = blockIdx.x * 16;
  for (int el = 0; el < 4; ++el) {
    int e = e0 + w * 4 + el;
    const size_t ro = (size_t)e * DP;
    float p[5];
    float mx = -1e30f;
#pragma unroll
    for (int u = 0; u < 5; ++u) {
      int d = u * 64 + lane;
      p[u] = (d < ND) ? att[ro + d] : -1e30f;
      mx = fmaxf(mx, p[u]);
    }
    for (int o = 32; o; o >>= 1) mx = fmaxf(mx, __shfl_xor(mx, o));
    float s = 0.f;
#pragma unroll
    for (int u = 0; u < 5; ++u) {
      int d = u * 64 + lane;
      float pe = (d < ND) ? expf(p[u] - mx) : 0.f;
      p[u] = pe;
      s += pe;
    }
    for (int o = 32; o; o >>= 1) s += __shfl_xor(s, o);
    float inv = 1.f / s;
#pragma unroll
    for (int u = 0; u < 5; ++u) {
      int d = u * 64 + lane;
      if (d < 304)
        efw[w * 4 + el][d] = (d < ND) ? (float)EF0[ro + d] * p[u] * inv : 0.f;
    }
  }
  __syncthreads();
  const int jl = lane & 15, kc = lane >> 4;
  const float alpha = alphaP[0];
  float acc[4][19];
#pragma unroll
  for (int ei = 0; ei < 4; ++ei)
#pragma unroll
    for (int jj = 0; jj < 19; ++jj) acc[ei][jj] = 0.f;
  const int d0 = kc * 75;
  const float* efw0 = &efw[w * 4 + 0][0];
  const float* efw1 = &efw[w * 4 + 1][0];
  const float* efw2 = &efw[w * 4 + 2][0];
  const float* efw3 = &efw[w * 4 + 3][0];
  for (int dd = 0; dd < 75; ++dd) {
    int d = d0 + dd;
    const float* wr = Wproj + (size_t)d * ND + jl;
    float w0 = efw0[d], w1 = efw1[d], w2 = efw2[d], w3 = efw3[d];
#pragma unroll
    for (int jj = 0; jj < 19; ++jj) {
      int j = jl + jj * 16;
      float wv = (j < ND) ? wr[jj * 16] : 0.f;
      acc[0][jj] += w0 * wv;
      acc[1][jj] += w1 * wv;
      acc[2][jj] += w2 * wv;
      acc[3][jj] += w3 * wv;
    }
  }
#pragma unroll
  for (int ei = 0; ei < 4; ++ei)
#pragma unroll
    for (int jj = 0; jj < 19; ++jj) {
      acc[ei][jj] += __shfl_xor(acc[ei][jj], 16);
      acc[ei][jj] += __shfl_xor(acc[ei][jj], 32);
    }
  float scp[4] = {0.f, 0.f, 0.f, 0.f};
#pragma unroll
  for (int ei = 0; ei < 4; ++ei) {
    int e = e0 + w * 4 + ei;
#pragma unroll
    for (int jj = 0; jj < 19; ++jj) {
      int j = jl + jj * 16;
      float v = 0.f;
      if (j < ND) {
        v = alpha * edge_feats[(size_t)e * ND + j] + (1.f - alpha) * acc[ei][jj];
        scp[ei] += v * ecWatt[j];
      }
      if (kc == 0) ef[(size_t)e * 304 + j] = v;
    }
  }
#pragma unroll
  for (int ei = 0; ei < 4; ++ei)
    for (int o = 8; o; o >>= 1) scp[ei] += __shfl_xor(scp[ei], o);
  if (lane == 0) {
#pragma unroll
    for (int ei = 0; ei < 4; ++ei) scores[e0 + w * 4 + ei] = scp[ei];
  }
}

// ---------------------------------------------------------------- k4ab: per-block softmax recompute + weighted pooling
__global__ __launch_bounds__(256) void k4ab_pool(const float* __restrict__ sc,
                                                 const float* __restrict__ ef,
                                                 float* __restrict__ pp) {
  __shared__ float redm[4];
  __shared__ float reds[4];
  __shared__ float wsh[64];
  const int t = threadIdx.x, lane = t & 63, w = t >> 6;
  float v[16];
  float mx = -1e30f;
#pragma unroll
  for (int u = 0; u < 16; ++u) {
    v[u] = sc[t + u * 256];
    mx = fmaxf(mx, v[u]);
  }
  for (int o = 32; o; o >>= 1) mx = fmaxf(mx, __shfl_xor(mx, o));
  if (lane == 0) redm[w] = mx;
  __syncthreads();
  float m2 = fmaxf(fmaxf(redm[0], redm[1]), fmaxf(redm[2], redm[3]));
  float s = 0.f;
#pragma unroll
  for (int u = 0; u < 16; ++u) s += expf(v[u] - m2);
  for (int o = 32; o; o >>= 1) s += __shfl_xor(s, o);
  if (lane == 0) reds[w] = s;
  __syncthreads();
  float inv = 1.f / (reds[0] + reds[1] + reds[2] + reds[3]);
  const int e0 = blockIdx.x * 64;
  if (t < 64) wsh[t] = expf(sc[e0 + t] - m2) * inv;
  __syncthreads();
  for (int j = t; j < 304; j += 256) {
    float acc = 0.f;
#pragma unroll 8
    for (int e = 0; e < 64; ++e) acc += wsh[e] * ef[(size_t)(e0 + e) * 304 + j];
    pp[blockIdx.x * 304 + j] = acc;
  }
}

// ---------------------------------------------------------------- k4c: final reduce + two matvecs -> 3 logits
__global__ __launch_bounds__(320) void k4c_final(const float* __restrict__ pp,
                                                 const float* __restrict__ ecWp,
                                                 const float* __restrict__ ecb,
                                                 const float* __restrict__ fcW,
                                                 const float* __restrict__ fcb,
                                                 float* __restrict__ out) {
  __shared__ float pooled[304];
  __shared__ float o[304];
  const int t = threadIdx.x;
  if (t < 304) {
    float acc = 0.f;
#pragma unroll 8
    for (int b = 0; b < 64; ++b) acc += pp[b * 304 + t];
    pooled[t] = acc;
  }
  __syncthreads();
  if (t < ND) {
    float acc = ecb[t];
#pragma unroll 4
    for (int j = 0; j < ND; ++j) acc += pooled[j] * ecWp[(size_t)j * ND + t];
    o[t] = acc;
  }
  __syncthreads();
  if (t < 64) {
#pragma unroll
    for (int c = 0; c < 3; ++c) {
      float a = 0.f;
      for (int j2 = t; j2 < ND; j2 += 64) a += o[j2] * fcW[j2 * 3 + c];
      for (int off = 32; off; off >>= 1) a += __shfl_xor(a, off);
      if (t == 0) out[c] = a + fcb[c];
    }
  }
}

// ----------------------------------------------------------------
extern "C" void kernel_launch(void* const* d_in, const int* in_sizes, int n_in,
                              void* d_out, int out_size, void* d_ws, size_t ws_size,
                              hipStream_t stream) {
  const float* X = (const float*)d_in[0];
  const float* EFEATS = (const float*)d_in[1];
  const float* INC = (const float*)d_in[2];
  const float* WATT = (const float*)d_in[3];
  const float* WPROJ = (const float*)d_in[4];
  const float* ALPHA = (const float*)d_in[5];
  const float* ECATT = (const float*)d_in[6];
  const float* ECWP = (const float*)d_in[7];
  const float* ECB = (const float*)d_in[8];
  const float* FCW = (const float*)d_in[9];
  const float* FCB = (const float*)d_in[10];

  char* ws = (char*)d_ws;
  f16* XT = (f16*)(ws);                    // [0, 10485760)
  f16* Zp = (f16*)(ws + 10485760);         // 16 x 2621440 B -> [10485760, 52428800)
  f16* WT = (f16*)(ws + 52428800);         // [52428800, 52633600)
  f16* EF0 = (f16*)(ws + 52633600);        // [52633600, 55255040)
  float* att = (float*)(ws + 55255040);    // [55255040, 60497920)
  float* ef = (float*)(ws + 60497920);     // [60497920, 65478656)
  float* sc = (float*)(ws + 65478656);     // 4096*4
  float* pp = (float*)(ws + 65495040);     // 64*304*4

  hipLaunchKernelGGL(k01_prep, dim3(656), dim3(256), 0, stream, X, WATT, XT, WT);
  hipLaunchKernelGGL(k2_bigmm, dim3(512), dim3(256), 0, stream, INC, XT, Zp);
  hipLaunchKernelGGL(k2bs_att, dim3(64), dim3(256), 0, stream, Zp, WT, EF0, att);
  hipLaunchKernelGGL(k3_edge, dim3(256), dim3(256), 0, stream, att, EF0, EFEATS,
                     WPROJ, ALPHA, ECATT, ef, sc);
  hipLaunchKernelGGL(k4ab_pool, dim3(64), dim3(256), 0, stream, sc, ef, pp);
  hipLaunchKernelGGL(k4c_final, dim3(1), dim3(320), 0, stream, pp, ECWP, ECB, FCW,
                     FCB, (float*)d_out);
}